// Round 8
// baseline (347.299 us; speedup 1.0000x reference)
//
#include <hip/hip_runtime.h>

#define HASH_BITS 19
#define HASH_SIZE (1u << HASH_BITS)
#define HASH_MASK (HASH_SIZE - 1)
#define EMPTY64 0xFFFFFFFFFFFFFFFFull
#define CH 256
#define PCH 32       // pairs per chunk in bucketed sparse kernels
#define NREP 8       // counter/bucket replicas (atomic de-contention)
#define NSEG (27 * NREP)
#define SEGCAP 4096  // pairs per (k,rep) segment
#define BM_WORDS 536704  // ceil(258^3 / 32), padded

typedef __attribute__((ext_vector_type(8))) short short8;
typedef __attribute__((ext_vector_type(4))) float floatx4;
typedef unsigned long long ull;

// split fp32 -> bf16 hi + bf16 lo (x ~= hi + lo, each RTN-even)
__device__ inline void bf16_split(float x, unsigned short& hi, unsigned short& lo) {
    unsigned u = __float_as_uint(x);
    unsigned r = u + (0x7FFFu + ((u >> 16) & 1u));
    hi = (unsigned short)(r >> 16);
    float hif = __uint_as_float(((unsigned)hi) << 16);
    float res = x - hif;
    unsigned v = __float_as_uint(res);
    unsigned rv = v + (0x7FFFu + ((v >> 16) & 1u));
    lo = (unsigned short)(rv >> 16);
}

__device__ inline void split8_pack(const float* xa, uint4& hv, uint4& lv) {
    unsigned short h[8], l[8];
#pragma unroll
    for (int q = 0; q < 8; ++q) bf16_split(xa[q], h[q], l[q]);
    hv.x = (unsigned)h[0] | ((unsigned)h[1] << 16);
    hv.y = (unsigned)h[2] | ((unsigned)h[3] << 16);
    hv.z = (unsigned)h[4] | ((unsigned)h[5] << 16);
    hv.w = (unsigned)h[6] | ((unsigned)h[7] << 16);
    lv.x = (unsigned)l[0] | ((unsigned)l[1] << 16);
    lv.y = (unsigned)l[2] | ((unsigned)l[3] << 16);
    lv.z = (unsigned)l[4] | ((unsigned)l[5] << 16);
    lv.w = (unsigned)l[6] | ((unsigned)l[7] << 16);
}

// async global->LDS, 16B per lane; lds base must be wave-uniform
__device__ __forceinline__ void gload_lds16(const void* g, void* l) {
    __builtin_amdgcn_global_load_lds(
        (const __attribute__((address_space(1))) unsigned int*)g,
        (__attribute__((address_space(3))) unsigned int*)l, 16, 0, 0);
}

// ---------------- hash build: fused (key<<32 | idx) single-load table ----------------
__global__ void hash_insert_k(const int* __restrict__ coords, int n,
                              ull* __restrict__ tbl, unsigned* __restrict__ keys,
                              unsigned* __restrict__ bm) {
    int i = blockIdx.x * blockDim.x + threadIdx.x;
    if (i >= n) return;
    unsigned cx = (unsigned)(coords[3 * i + 0] + 1);
    unsigned cy = (unsigned)(coords[3 * i + 1] + 1);
    unsigned cz = (unsigned)(coords[3 * i + 2] + 1);
    unsigned key = (cx * 258u + cy) * 258u + cz;
    keys[i] = key;
    atomicOr(&bm[key >> 5], 1u << (key & 31));
    ull e = ((ull)key << 32) | (unsigned)i;
    unsigned h = (key * 2654435761u) & HASH_MASK;
    while (true) {
        ull prev = atomicCAS(&tbl[h], EMPTY64, e);
        if (prev == EMPTY64) return;
        h = (h + 1) & HASH_MASK;
    }
}

// ---------------- neighbor pairs: bitmap prefilter, replicated counters ----------------
__global__ void neighbor_bm_k(const unsigned* __restrict__ keys, int n,
                              const unsigned* __restrict__ bm,
                              const ull* __restrict__ tbl,
                              int2* __restrict__ buckets, int* __restrict__ kcnt) {
    int t = blockIdx.x * blockDim.x + threadIdx.x;
    if (t >= n * 9) return;
    int rep = blockIdx.x & (NREP - 1);
    int i = t / 9, r = t - i * 9;            // r = (dx+1)*3 + (dy+1)
    unsigned key = keys[i];
    int base = (int)key + ((r / 3 - 1) * 258 + (r % 3 - 1)) * 258;
    unsigned bA = base - 1, bB = base, bC = base + 1;
    unsigned hit0 = (bm[bA >> 5] >> (bA & 31)) & 1u;
    unsigned hit1 = (bm[bB >> 5] >> (bB & 31)) & 1u;
    unsigned hit2 = (bm[bC >> 5] >> (bC & 31)) & 1u;
#pragma unroll
    for (int dz = -1; dz <= 1; ++dz) {
        if (r == 4 && dz == 0) continue;     // center handled densely
        unsigned hit = dz < 0 ? hit0 : (dz == 0 ? hit1 : hit2);
        if (!hit) continue;
        unsigned nk = (unsigned)(base + dz);
        unsigned h = (nk * 2654435761u) & HASH_MASK;
        int j = -1;
        while (true) {
            ull e = tbl[h];
            if ((unsigned)(e >> 32) == nk) { j = (int)(e & 0xFFFFFFFFu); break; }
            if (e == EMPTY64) break;
            h = (h + 1) & HASH_MASK;
        }
        if (j >= 0) {
            int kk = 3 * r + dz + 1;
            int seg = kk * NREP + rep;
            int pos = atomicAdd(&kcnt[seg * 16], 1);
            buckets[(size_t)seg * SEGCAP + pos] = make_int2(i, j);
        }
    }
}

// ---------------- chunk descriptors over NSEG segments ----------------
__global__ void chunk_desc_k(const int* __restrict__ kcnt,
                             int2* __restrict__ desc, int* __restrict__ nchunks) {
    __shared__ int cnts[NSEG];
    __shared__ int offs[NSEG + 1];
    int t = threadIdx.x;
    if (t < NSEG) cnts[t] = kcnt[t * 16];
    __syncthreads();
    if (t == 0) {
        int acc = 0;
        for (int s = 0; s < NSEG; ++s) { offs[s] = acc; acc += (cnts[s] + PCH - 1) / PCH; }
        offs[NSEG] = acc;
        *nchunks = acc;
    }
    __syncthreads();
    if (t < NSEG) {
        int cnt = cnts[t];
        int o = offs[t];
        int k = t / NREP;
        for (int c = 0; c * PCH < cnt; ++c) {
            int len = min(PCH, cnt - c * PCH);
            desc[o + c] = make_int2(t * SEGCAP + c * PCH, (k << 8) | len);
        }
    }
}

// ---------------- pre-split ALL 27 W slices into MFMA-fragment-ordered bf16 image ----------
// image layout: [k(27)][kk(8)][nt(16)][lane(64)][j(8)] shorts
// cin = kk*32 + (lane>>4)*8 + j,  cout = nt*16 + (lane&15)
__global__ void prep_w_all_k(const float* __restrict__ W, unsigned short* __restrict__ Whi,
                             unsigned short* __restrict__ Wlo) {
    int tt = blockIdx.x * 256 + threadIdx.x;
    if (tt >= 27 * 65536) return;
    int k = tt >> 16, rem = tt & 65535, cin = rem >> 8, cout = rem & 255;
    float w = W[tt];
    unsigned short hb, lb;
    bf16_split(w, hb, lb);
    int kk = cin >> 5, kg = (cin >> 3) & 3, j = cin & 7, nt = cout >> 4, lc = cout & 15;
    size_t idx = ((((size_t)(k * 8 + kk) * 16 + nt) * 64) + kg * 16 + lc) * 8 + j;
    Whi[idx] = hb;
    Wlo[idx] = lb;
}

// ---------------- layer 1: Cin=2 -> 256, dense center ----------------
__global__ void dense1_k(const float* __restrict__ x, const float* __restrict__ Wc,
                         float* __restrict__ out, int n) {
    int t = blockIdx.x * blockDim.x + threadIdx.x;
    if (t >= n * CH) return;
    int i = t >> 8, co = t & 255;
    float2 xv = *reinterpret_cast<const float2*>(x + 2 * i);
    out[t] = fmaf(xv.x, Wc[co], xv.y * Wc[CH + co]);
}

__global__ void sparse1b_k(const float* __restrict__ feats, const float* __restrict__ W1,
                           float* __restrict__ out, const int2* __restrict__ buckets,
                           const int2* __restrict__ desc, const int* __restrict__ nchunks) {
    __shared__ float xs[PCH][2];
    __shared__ int ii[PCH];
    int nc = *nchunks;
    int t = threadIdx.x;
    for (int m = blockIdx.x; m < nc; m += gridDim.x) {
        int2 d = desc[m];
        int k = d.y >> 8, len = d.y & 255;
        if (t < PCH) {
            if (t < len) {
                int2 pr = buckets[d.x + t];
                ii[t] = pr.x;
                xs[t][0] = feats[2 * pr.y];
                xs[t][1] = feats[2 * pr.y + 1];
            } else {
                ii[t] = -1;
                xs[t][0] = 0.f; xs[t][1] = 0.f;
            }
        }
        __syncthreads();
        const float* Wk = W1 + (size_t)k * 2 * CH;
        float w0 = Wk[t], w1 = Wk[CH + t];
#pragma unroll
        for (int p = 0; p < PCH; ++p) {
            int i = ii[p];
            if (i >= 0) atomicAdd(&out[(size_t)i * CH + t], fmaf(xs[p][0], w0, xs[p][1] * w1));
        }
        __syncthreads();
    }
}

// ---------------- mid layers dense center: 128-row tile, B via global_load_lds ----------
// A: single LDS buffer [512 slots][8] (hi+lo), staged with T14 split (load-early/write-late).
// B: LDS double buffer, DMA'd with global_load_lds (no VGPR round trip).
// Per kk: dmaB(kk+1) ; loadA-regs(kk+1) ; compute(kk) ; barrier ; split+write A ; barrier.
__global__ __launch_bounds__(256, 2) void dense_mid_mfma_k(
        const float* __restrict__ x,
        const unsigned short* __restrict__ Whi,
        const unsigned short* __restrict__ Wlo,
        float* __restrict__ out, int n) {
    __shared__ unsigned short AsH[4096], AsL[4096];   // 512 slots * 8 shorts
    __shared__ unsigned short Bs[2][2][8192];         // [buf][hi/lo][16 nt * 64 lane * 8]
    int t = threadIdx.x;
    int wid = t >> 6, lane = t & 63;
    int i0 = blockIdx.x * 128;

    floatx4 acc[8][4];
#pragma unroll
    for (int a = 0; a < 8; ++a)
#pragma unroll
        for (int b = 0; b < 4; ++b) acc[a][b] = floatx4{0.f, 0.f, 0.f, 0.f};

    // staging roles: thread t stages slots t and t+256 (linear -> conflict-free)
    // slot S: mt = S>>6, row = mt*16 + (S&15), kg = (S>>4)&3
    const float* sp[2];
    float sok[2];
    int slots[2] = {t, t + 256};
#pragma unroll
    for (int s = 0; s < 2; ++s) {
        int S = slots[s];
        int row = ((S >> 6) << 4) + (S & 15);
        int kg = (S >> 4) & 3;
        sok[s] = (i0 + row < n) ? 1.f : 0.f;
        sp[s] = x + (size_t)min(i0 + row, n - 1) * CH + kg * 8;
    }

    floatx4 ra[2][2];

    auto dmaB = [&](int kk, int b) {
#pragma unroll
        for (int c = 0; c < 4; ++c) {
            int go = c * 2048 + t * 8;                  // shorts, includes lane offset
            int lo_ = c * 2048 + wid * 512;             // wave-uniform lds base (shorts)
            gload_lds16(Whi + kk * 8192 + go, &Bs[b][0][lo_]);
            gload_lds16(Wlo + kk * 8192 + go, &Bs[b][1][lo_]);
        }
    };
    auto loadA = [&](int kk) {
#pragma unroll
        for (int s = 0; s < 2; ++s) {
            ra[s][0] = *(const floatx4*)(sp[s] + kk * 32);
            ra[s][1] = *(const floatx4*)(sp[s] + kk * 32 + 4);
        }
    };
    auto splitWriteA = [&]() {
#pragma unroll
        for (int s = 0; s < 2; ++s) {
            float xa[8];
            xa[0] = ra[s][0].x * sok[s]; xa[1] = ra[s][0].y * sok[s];
            xa[2] = ra[s][0].z * sok[s]; xa[3] = ra[s][0].w * sok[s];
            xa[4] = ra[s][1].x * sok[s]; xa[5] = ra[s][1].y * sok[s];
            xa[6] = ra[s][1].z * sok[s]; xa[7] = ra[s][1].w * sok[s];
            uint4 hv, lv;
            split8_pack(xa, hv, lv);
            *(uint4*)&AsH[slots[s] * 8] = hv;
            *(uint4*)&AsL[slots[s] * 8] = lv;
        }
    };
    auto compute = [&](int b) {
        short8 bh[4], bl[4];
#pragma unroll
        for (int q = 0; q < 4; ++q) {
            int fo = ((wid * 4 + q) * 64 + lane) * 8;
            bh[q] = *(const short8*)&Bs[b][0][fo];
            bl[q] = *(const short8*)&Bs[b][1][fo];
        }
#pragma unroll
        for (int mt = 0; mt < 8; ++mt) {
            short8 ah = *(const short8*)&AsH[(mt * 64 + lane) * 8];
            short8 al = *(const short8*)&AsL[(mt * 64 + lane) * 8];
#pragma unroll
            for (int q = 0; q < 4; ++q) {
                acc[mt][q] = __builtin_amdgcn_mfma_f32_16x16x32_bf16(ah, bh[q], acc[mt][q], 0, 0, 0);
                acc[mt][q] = __builtin_amdgcn_mfma_f32_16x16x32_bf16(al, bh[q], acc[mt][q], 0, 0, 0);
                acc[mt][q] = __builtin_amdgcn_mfma_f32_16x16x32_bf16(ah, bl[q], acc[mt][q], 0, 0, 0);
            }
        }
    };

    // prologue: B(0) DMA + A(0) stage
    dmaB(0, 0);
    loadA(0);
    splitWriteA();
    __syncthreads();   // drains vmcnt (B0 in LDS) + lgkm (A0 visible)

#pragma unroll
    for (int kk = 0; kk < 8; ++kk) {
        if (kk < 7) {
            dmaB(kk + 1, (kk + 1) & 1);   // lands during compute; drained at next barrier
            loadA(kk + 1);                // x loads hidden under MFMA
        }
        compute(kk & 1);
        __syncthreads();
        if (kk < 7) {
            splitWriteA();
            __syncthreads();
        }
    }

    // epilogue: D row=(lane>>4)*4+reg, col=lane&15
    int r0 = (lane >> 4) * 4, c0 = lane & 15;
#pragma unroll
    for (int mt = 0; mt < 8; ++mt)
#pragma unroll
        for (int r = 0; r < 4; ++r) {
            int row = i0 + mt * 16 + r0 + r;
            if (row < n) {
#pragma unroll
                for (int q = 0; q < 4; ++q)
                    out[(size_t)row * CH + wid * 64 + q * 16 + c0] = acc[mt][q][r];
            }
        }
}

// ---------------- mid layers sparse: 32 gathered rows per chunk, 3-pass MFMA ----------------
__global__ __launch_bounds__(256) void sparse_mid_mfma_k(
        const float* __restrict__ x,
        const unsigned short* __restrict__ Whi,
        const unsigned short* __restrict__ Wlo,
        float* __restrict__ out, const int2* __restrict__ buckets,
        const int2* __restrict__ desc, const int* __restrict__ nchunks) {
    // A image: [kk(8)][mt(2)][lane(64)][j(8)]
    __shared__ unsigned short As_hi[8192];
    __shared__ unsigned short As_lo[8192];
    __shared__ int ii[PCH];
    int nc = *nchunks;
    int t = threadIdx.x;
    int wid = t >> 6, lane = t & 63;
    int r = t >> 3, kk0 = t & 7;          // 8 threads per gathered row
    int mt_s = r >> 4, rl = r & 15;
    for (int m = blockIdx.x; m < nc; m += gridDim.x) {
        int2 d = desc[m];
        int k = d.y >> 8, len = d.y & 255;
        // ---- stage A (full K=256 for 32 rows), split hi/lo ----
        if (r < len) {
            int2 pr = buckets[d.x + r];
            if (kk0 == 0) ii[r] = pr.x;
            const float* src = x + (size_t)pr.y * CH + kk0 * 32;
#pragma unroll
            for (int kg = 0; kg < 4; ++kg) {
                float xa[8];
                floatx4 v0 = *(const floatx4*)(src + kg * 8);
                floatx4 v1 = *(const floatx4*)(src + kg * 8 + 4);
                xa[0] = v0.x; xa[1] = v0.y; xa[2] = v0.z; xa[3] = v0.w;
                xa[4] = v1.x; xa[5] = v1.y; xa[6] = v1.z; xa[7] = v1.w;
                uint4 hv, lv;
                split8_pack(xa, hv, lv);
                int ab = ((kk0 * 2 + mt_s) * 64 + kg * 16 + rl) * 8;
                *(uint4*)&As_hi[ab] = hv;
                *(uint4*)&As_lo[ab] = lv;
            }
        } else {
            if (kk0 == 0) ii[r] = -1;
            uint4 z = {0, 0, 0, 0};
#pragma unroll
            for (int kg = 0; kg < 4; ++kg) {
                int ab = ((kk0 * 2 + mt_s) * 64 + kg * 16 + rl) * 8;
                *(uint4*)&As_hi[ab] = z;
                *(uint4*)&As_lo[ab] = z;
            }
        }
        __syncthreads();
        floatx4 acc[2][4];
#pragma unroll
        for (int a = 0; a < 2; ++a)
#pragma unroll
            for (int b = 0; b < 4; ++b) acc[a][b] = floatx4{0.f, 0.f, 0.f, 0.f};
        for (int kk = 0; kk < 8; ++kk) {
            short8 ah0 = *(const short8*)&As_hi[((kk * 2 + 0) * 64 + lane) * 8];
            short8 al0 = *(const short8*)&As_lo[((kk * 2 + 0) * 64 + lane) * 8];
            short8 ah1 = *(const short8*)&As_hi[((kk * 2 + 1) * 64 + lane) * 8];
            short8 al1 = *(const short8*)&As_lo[((kk * 2 + 1) * 64 + lane) * 8];
#pragma unroll
            for (int q = 0; q < 4; ++q) {
                int nt = wid * 4 + q;
                size_t off = (((size_t)(k * 8 + kk) * 16 + nt) * 64 + lane) * 8;
                short8 bh = *(const short8*)&Whi[off];   // B direct global->VGPR (used once)
                short8 bl = *(const short8*)&Wlo[off];
                acc[0][q] = __builtin_amdgcn_mfma_f32_16x16x32_bf16(ah0, bh, acc[0][q], 0, 0, 0);
                acc[0][q] = __builtin_amdgcn_mfma_f32_16x16x32_bf16(al0, bh, acc[0][q], 0, 0, 0);
                acc[0][q] = __builtin_amdgcn_mfma_f32_16x16x32_bf16(ah0, bl, acc[0][q], 0, 0, 0);
                acc[1][q] = __builtin_amdgcn_mfma_f32_16x16x32_bf16(ah1, bh, acc[1][q], 0, 0, 0);
                acc[1][q] = __builtin_amdgcn_mfma_f32_16x16x32_bf16(al1, bh, acc[1][q], 0, 0, 0);
                acc[1][q] = __builtin_amdgcn_mfma_f32_16x16x32_bf16(ah1, bl, acc[1][q], 0, 0, 0);
            }
        }
        // ---- epilogue: atomic accumulate ----
        int r0 = (lane >> 4) * 4, c0 = lane & 15;
#pragma unroll
        for (int mt = 0; mt < 2; ++mt)
#pragma unroll
            for (int rr = 0; rr < 4; ++rr) {
                int row = mt * 16 + r0 + rr;
                int i = ii[row];
                if (i >= 0) {
#pragma unroll
                    for (int q = 0; q < 4; ++q)
                        atomicAdd(&out[(size_t)i * CH + wid * 64 + q * 16 + c0], acc[mt][q][rr]);
                }
            }
        __syncthreads();
    }
}

// ---------------- layer 4: 256 -> 2 ----------------
__device__ inline float wave_sum(float v) {
    for (int off = 32; off; off >>= 1) v += __shfl_xor(v, off);
    return v;
}

__global__ void dense4_k(const float* __restrict__ x, const float* __restrict__ Wc,
                         float* __restrict__ out, int n) {
    int wid = threadIdx.x >> 6, lane = threadIdx.x & 63;
    int i = blockIdx.x * 4 + wid;
    if (i >= n) return;
    floatx4 xv = *reinterpret_cast<const floatx4*>(x + (size_t)i * CH + lane * 4);
    floatx4 w0 = *reinterpret_cast<const floatx4*>(Wc + lane * 8);
    floatx4 w1 = *reinterpret_cast<const floatx4*>(Wc + lane * 8 + 4);
    float a0 = xv.x * w0.x + xv.y * w0.z + xv.z * w1.x + xv.w * w1.z;
    float a1 = xv.x * w0.y + xv.y * w0.w + xv.z * w1.y + xv.w * w1.w;
    a0 = wave_sum(a0);
    a1 = wave_sum(a1);
    if (lane == 0) { out[2 * i] = a0; out[2 * i + 1] = a1; }
}

__global__ void sparse4b_k(const float* __restrict__ x, const float* __restrict__ W4,
                           float* __restrict__ out, const int2* __restrict__ buckets,
                           const int2* __restrict__ desc, const int* __restrict__ nchunks) {
    int nc = *nchunks;
    int wid = threadIdx.x >> 6, lane = threadIdx.x & 63;
    for (int m = blockIdx.x; m < nc; m += gridDim.x) {
        int2 d = desc[m];
        int k = d.y >> 8, len = d.y & 255;
        const float* Wk = W4 + (size_t)k * CH * 2;
        floatx4 w0 = *reinterpret_cast<const floatx4*>(Wk + lane * 8);
        floatx4 w1 = *reinterpret_cast<const floatx4*>(Wk + lane * 8 + 4);
        for (int p = wid; p < len; p += 4) {
            int2 pr = buckets[d.x + p];
            floatx4 xv = *reinterpret_cast<const floatx4*>(x + (size_t)pr.y * CH + lane * 4);
            float a0 = xv.x * w0.x + xv.y * w0.z + xv.z * w1.x + xv.w * w1.z;
            float a1 = xv.x * w0.y + xv.y * w0.w + xv.z * w1.y + xv.w * w1.w;
            a0 = wave_sum(a0);
            a1 = wave_sum(a1);
            if (lane == 0) {
                atomicAdd(&out[2 * pr.x], a0);
                atomicAdd(&out[2 * pr.x + 1], a1);
            }
        }
    }
}

extern "C" void kernel_launch(void* const* d_in, const int* in_sizes, int n_in,
                              void* d_out, int out_size, void* d_ws, size_t ws_size,
                              hipStream_t stream) {
    const int* coords = (const int*)d_in[0];
    const float* feats = (const float*)d_in[1];
    const float* W1 = (const float*)d_in[2];
    const float* W2 = (const float*)d_in[3];
    const float* W3 = (const float*)d_in[4];
    const float* W4 = (const float*)d_in[5];
    float* out = (float*)d_out;
    int n = in_sizes[0] / 3;

    char* ws = (char*)d_ws;
    auto alloc = [&](size_t bytes) -> void* {
        void* p = (void*)ws;
        ws += (bytes + 255) & ~(size_t)255;
        return p;
    };
    ull* tbl = (ull*)alloc((size_t)HASH_SIZE * 8);
    unsigned* bm = (unsigned*)alloc((size_t)BM_WORDS * 4);
    unsigned* keys = (unsigned*)alloc((size_t)n * 4);
    int* kcnt = (int*)alloc((size_t)NSEG * 16 * 4);   // 1 counter per 64B line
    int* nchunks = (int*)alloc(4);
    int ndesc = NSEG * (SEGCAP / PCH);
    int2* desc = (int2*)alloc(sizeof(int2) * (size_t)ndesc);
    int2* buckets = (int2*)alloc(sizeof(int2) * (size_t)NSEG * SEGCAP);
    unsigned short* Whi2 = (unsigned short*)alloc((size_t)27 * 65536 * 2);
    unsigned short* Wlo2 = (unsigned short*)alloc((size_t)27 * 65536 * 2);
    unsigned short* Whi3 = (unsigned short*)alloc((size_t)27 * 65536 * 2);
    unsigned short* Wlo3 = (unsigned short*)alloc((size_t)27 * 65536 * 2);
    float* x1 = (float*)alloc((size_t)n * CH * 4);
    float* x2 = (float*)alloc((size_t)n * CH * 4);

    hipMemsetAsync(tbl, 0xFF, (size_t)HASH_SIZE * 8, stream);
    hipMemsetAsync(bm, 0, (size_t)BM_WORDS * 4, stream);
    hipMemsetAsync(kcnt, 0, (size_t)NSEG * 16 * 4, stream);

    hash_insert_k<<<(n + 255) / 256, 256, 0, stream>>>(coords, n, tbl, keys, bm);
    neighbor_bm_k<<<(n * 9 + 255) / 256, 256, 0, stream>>>(keys, n, bm, tbl, buckets, kcnt);
    chunk_desc_k<<<1, 256, 0, stream>>>(kcnt, desc, nchunks);
    prep_w_all_k<<<(27 * 65536) / 256, 256, 0, stream>>>(W2, Whi2, Wlo2);
    prep_w_all_k<<<(27 * 65536) / 256, 256, 0, stream>>>(W3, Whi3, Wlo3);

    int mtiles = (n + 127) / 128;

    // layer 1: 2 -> 256
    dense1_k<<<(n * CH + 255) / 256, 256, 0, stream>>>(feats, W1 + 13 * 2 * CH, x1, n);
    sparse1b_k<<<1024, 256, 0, stream>>>(feats, W1, x1, buckets, desc, nchunks);

    // layer 2: 256 -> 256
    dense_mid_mfma_k<<<mtiles, 256, 0, stream>>>(x1, Whi2 + (size_t)13 * 65536,
                                                 Wlo2 + (size_t)13 * 65536, x2, n);
    sparse_mid_mfma_k<<<512, 256, 0, stream>>>(x1, Whi2, Wlo2, x2, buckets, desc, nchunks);

    // layer 3: 256 -> 256
    dense_mid_mfma_k<<<mtiles, 256, 0, stream>>>(x2, Whi3 + (size_t)13 * 65536,
                                                 Wlo3 + (size_t)13 * 65536, x1, n);
    sparse_mid_mfma_k<<<512, 256, 0, stream>>>(x2, Whi3, Wlo3, x1, buckets, desc, nchunks);

    // layer 4: 256 -> 2
    dense4_k<<<(n + 3) / 4, 256, 0, stream>>>(x1, W4 + 13 * CH * 2, out, n);
    sparse4b_k<<<512, 256, 0, stream>>>(x1, W4, out, buckets, desc, nchunks);
}

// Round 9
// 327.495 us; speedup vs baseline: 1.0605x; 1.0605x over previous
//
#include <hip/hip_runtime.h>

#define HASH_BITS 19
#define HASH_SIZE (1u << HASH_BITS)
#define HASH_MASK (HASH_SIZE - 1)
#define EMPTY64 0xFFFFFFFFFFFFFFFFull
#define CH 256
#define PCH 32       // pairs per chunk in bucketed sparse kernels
#define NREP 8       // counter/bucket replicas (atomic de-contention)
#define NSEG (27 * NREP)
#define SEGCAP 4096  // pairs per (k,rep) segment
#define BM_WORDS 536704  // ceil(258^3 / 32), padded

typedef __attribute__((ext_vector_type(8))) short short8;
typedef __attribute__((ext_vector_type(4))) float floatx4;
typedef unsigned long long ull;

// split fp32 -> bf16 hi + bf16 lo (x ~= hi + lo, each RTN-even)
__device__ inline void bf16_split(float x, unsigned short& hi, unsigned short& lo) {
    unsigned u = __float_as_uint(x);
    unsigned r = u + (0x7FFFu + ((u >> 16) & 1u));
    hi = (unsigned short)(r >> 16);
    float hif = __uint_as_float(((unsigned)hi) << 16);
    float res = x - hif;
    unsigned v = __float_as_uint(res);
    unsigned rv = v + (0x7FFFu + ((v >> 16) & 1u));
    lo = (unsigned short)(rv >> 16);
}

__device__ inline void split8_pack(const float* xa, uint4& hv, uint4& lv) {
    unsigned short h[8], l[8];
#pragma unroll
    for (int q = 0; q < 8; ++q) bf16_split(xa[q], h[q], l[q]);
    hv.x = (unsigned)h[0] | ((unsigned)h[1] << 16);
    hv.y = (unsigned)h[2] | ((unsigned)h[3] << 16);
    hv.z = (unsigned)h[4] | ((unsigned)h[5] << 16);
    hv.w = (unsigned)h[6] | ((unsigned)h[7] << 16);
    lv.x = (unsigned)l[0] | ((unsigned)l[1] << 16);
    lv.y = (unsigned)l[2] | ((unsigned)l[3] << 16);
    lv.z = (unsigned)l[4] | ((unsigned)l[5] << 16);
    lv.w = (unsigned)l[6] | ((unsigned)l[7] << 16);
}

// ---------------- hash build: fused (key<<32 | idx) single-load table ----------------
__global__ void hash_insert_k(const int* __restrict__ coords, int n,
                              ull* __restrict__ tbl, unsigned* __restrict__ keys,
                              unsigned* __restrict__ bm) {
    int i = blockIdx.x * blockDim.x + threadIdx.x;
    if (i >= n) return;
    unsigned cx = (unsigned)(coords[3 * i + 0] + 1);
    unsigned cy = (unsigned)(coords[3 * i + 1] + 1);
    unsigned cz = (unsigned)(coords[3 * i + 2] + 1);
    unsigned key = (cx * 258u + cy) * 258u + cz;
    keys[i] = key;
    atomicOr(&bm[key >> 5], 1u << (key & 31));
    ull e = ((ull)key << 32) | (unsigned)i;
    unsigned h = (key * 2654435761u) & HASH_MASK;
    while (true) {
        ull prev = atomicCAS(&tbl[h], EMPTY64, e);
        if (prev == EMPTY64) return;
        h = (h + 1) & HASH_MASK;
    }
}

// ---------------- neighbor pairs: bitmap prefilter, replicated counters ----------------
__global__ void neighbor_bm_k(const unsigned* __restrict__ keys, int n,
                              const unsigned* __restrict__ bm,
                              const ull* __restrict__ tbl,
                              int2* __restrict__ buckets, int* __restrict__ kcnt) {
    int t = blockIdx.x * blockDim.x + threadIdx.x;
    if (t >= n * 9) return;
    int rep = blockIdx.x & (NREP - 1);
    int i = t / 9, r = t - i * 9;            // r = (dx+1)*3 + (dy+1)
    unsigned key = keys[i];
    int base = (int)key + ((r / 3 - 1) * 258 + (r % 3 - 1)) * 258;
    unsigned bA = base - 1, bB = base, bC = base + 1;
    unsigned hit0 = (bm[bA >> 5] >> (bA & 31)) & 1u;
    unsigned hit1 = (bm[bB >> 5] >> (bB & 31)) & 1u;
    unsigned hit2 = (bm[bC >> 5] >> (bC & 31)) & 1u;
#pragma unroll
    for (int dz = -1; dz <= 1; ++dz) {
        if (r == 4 && dz == 0) continue;     // center handled densely
        unsigned hit = dz < 0 ? hit0 : (dz == 0 ? hit1 : hit2);
        if (!hit) continue;
        unsigned nk = (unsigned)(base + dz);
        unsigned h = (nk * 2654435761u) & HASH_MASK;
        int j = -1;
        while (true) {
            ull e = tbl[h];
            if ((unsigned)(e >> 32) == nk) { j = (int)(e & 0xFFFFFFFFu); break; }
            if (e == EMPTY64) break;
            h = (h + 1) & HASH_MASK;
        }
        if (j >= 0) {
            int kk = 3 * r + dz + 1;
            int seg = kk * NREP + rep;
            int pos = atomicAdd(&kcnt[seg * 16], 1);
            buckets[(size_t)seg * SEGCAP + pos] = make_int2(i, j);
        }
    }
}

// ---------------- chunk descriptors over NSEG segments ----------------
__global__ void chunk_desc_k(const int* __restrict__ kcnt,
                             int2* __restrict__ desc, int* __restrict__ nchunks) {
    __shared__ int cnts[NSEG];
    __shared__ int offs[NSEG + 1];
    int t = threadIdx.x;
    if (t < NSEG) cnts[t] = kcnt[t * 16];
    __syncthreads();
    if (t == 0) {
        int acc = 0;
        for (int s = 0; s < NSEG; ++s) { offs[s] = acc; acc += (cnts[s] + PCH - 1) / PCH; }
        offs[NSEG] = acc;
        *nchunks = acc;
    }
    __syncthreads();
    if (t < NSEG) {
        int cnt = cnts[t];
        int o = offs[t];
        int k = t / NREP;
        for (int c = 0; c * PCH < cnt; ++c) {
            int len = min(PCH, cnt - c * PCH);
            desc[o + c] = make_int2(t * SEGCAP + c * PCH, (k << 8) | len);
        }
    }
}

// ---------------- pre-split ALL 27 W slices into MFMA-fragment-ordered bf16 image ----------
// image layout: [k(27)][kk(8)][nt(16)][lane(64)][j(8)] shorts
// cin = kk*32 + (lane>>4)*8 + j,  cout = nt*16 + (lane&15)
__global__ void prep_w_all_k(const float* __restrict__ W, unsigned short* __restrict__ Whi,
                             unsigned short* __restrict__ Wlo) {
    int tt = blockIdx.x * 256 + threadIdx.x;
    if (tt >= 27 * 65536) return;
    int k = tt >> 16, rem = tt & 65535, cin = rem >> 8, cout = rem & 255;
    float w = W[tt];
    unsigned short hb, lb;
    bf16_split(w, hb, lb);
    int kk = cin >> 5, kg = (cin >> 3) & 3, j = cin & 7, nt = cout >> 4, lc = cout & 15;
    size_t idx = ((((size_t)(k * 8 + kk) * 16 + nt) * 64) + kg * 16 + lc) * 8 + j;
    Whi[idx] = hb;
    Wlo[idx] = lb;
}

// ---------------- layer 1: Cin=2 -> 256, dense center ----------------
__global__ void dense1_k(const float* __restrict__ x, const float* __restrict__ Wc,
                         float* __restrict__ out, int n) {
    int t = blockIdx.x * blockDim.x + threadIdx.x;
    if (t >= n * CH) return;
    int i = t >> 8, co = t & 255;
    float2 xv = *reinterpret_cast<const float2*>(x + 2 * i);
    out[t] = fmaf(xv.x, Wc[co], xv.y * Wc[CH + co]);
}

__global__ void sparse1b_k(const float* __restrict__ feats, const float* __restrict__ W1,
                           float* __restrict__ out, const int2* __restrict__ buckets,
                           const int2* __restrict__ desc, const int* __restrict__ nchunks) {
    __shared__ float xs[PCH][2];
    __shared__ int ii[PCH];
    int nc = *nchunks;
    int t = threadIdx.x;
    for (int m = blockIdx.x; m < nc; m += gridDim.x) {
        int2 d = desc[m];
        int k = d.y >> 8, len = d.y & 255;
        if (t < PCH) {
            if (t < len) {
                int2 pr = buckets[d.x + t];
                ii[t] = pr.x;
                xs[t][0] = feats[2 * pr.y];
                xs[t][1] = feats[2 * pr.y + 1];
            } else {
                ii[t] = -1;
                xs[t][0] = 0.f; xs[t][1] = 0.f;
            }
        }
        __syncthreads();
        const float* Wk = W1 + (size_t)k * 2 * CH;
        float w0 = Wk[t], w1 = Wk[CH + t];
#pragma unroll
        for (int p = 0; p < PCH; ++p) {
            int i = ii[p];
            if (i >= 0) atomicAdd(&out[(size_t)i * CH + t], fmaf(xs[p][0], w0, xs[p][1] * w1));
        }
        __syncthreads();
    }
}

// ---------------- mid layers dense center: M=64, A triple-buffer, 1 barrier/kk ----------
// A LDS: 3 buffers of [256 slots][8] shorts; thread t writes slot t (byte-linear,
// conflict-free); MFMA lane l reads slot mt*64+l (16B stride, 2 lanes/bank = free).
// Pipeline per kk: loadB(kk+1)->regs ; loadA(kk+2)->regs ; compute(kk) ;
// splitWriteA(kk+2) ; barrier.   (x latency covered by ~2 kk-periods)
__global__ __launch_bounds__(256) void dense_mid_mfma_k(
        const float* __restrict__ x,
        const unsigned short* __restrict__ Whi,
        const unsigned short* __restrict__ Wlo,
        float* __restrict__ out, int n) {
    __shared__ unsigned short AsH[3][2048], AsL[3][2048];
    int t = threadIdx.x;
    int wid = t >> 6, lane = t & 63;
    int i0 = blockIdx.x * 64;

    floatx4 acc[4][4];
#pragma unroll
    for (int a = 0; a < 4; ++a)
#pragma unroll
        for (int b = 0; b < 4; ++b) acc[a][b] = floatx4{0.f, 0.f, 0.f, 0.f};

    // staging role: thread t -> slot t: row = (t>>6)*16 + (t&15), kg = (t>>4)&3
    int row = ((t >> 6) << 4) + (t & 15);
    int kg = (t >> 4) & 3;
    float sok = (i0 + row < n) ? 1.f : 0.f;
    const float* sp = x + (size_t)min(i0 + row, n - 1) * CH + kg * 8;

    floatx4 ra0, ra1;
    short8 Bh[2][4], Bl[2][4];

    auto loadB = [&](int kk, int b) {
#pragma unroll
        for (int q = 0; q < 4; ++q) {
            size_t off = (((size_t)kk * 16 + wid * 4 + q) * 64 + lane) * 8;
            Bh[b][q] = *(const short8*)&Whi[off];
            Bl[b][q] = *(const short8*)&Wlo[off];
        }
    };
    auto loadA = [&](int kk) {
        ra0 = *(const floatx4*)(sp + kk * 32);
        ra1 = *(const floatx4*)(sp + kk * 32 + 4);
    };
    auto writeA = [&](int bi) {
        float xa[8];
        xa[0] = ra0.x * sok; xa[1] = ra0.y * sok; xa[2] = ra0.z * sok; xa[3] = ra0.w * sok;
        xa[4] = ra1.x * sok; xa[5] = ra1.y * sok; xa[6] = ra1.z * sok; xa[7] = ra1.w * sok;
        uint4 hv, lv;
        split8_pack(xa, hv, lv);
        *(uint4*)&AsH[bi][t * 8] = hv;
        *(uint4*)&AsL[bi][t * 8] = lv;
    };
    auto compute = [&](int bi, int b) {
#pragma unroll
        for (int mt = 0; mt < 4; ++mt) {
            short8 ah = *(const short8*)&AsH[bi][(mt * 64 + lane) * 8];
            short8 al = *(const short8*)&AsL[bi][(mt * 64 + lane) * 8];
#pragma unroll
            for (int q = 0; q < 4; ++q) {
                acc[mt][q] = __builtin_amdgcn_mfma_f32_16x16x32_bf16(ah, Bh[b][q], acc[mt][q], 0, 0, 0);
                acc[mt][q] = __builtin_amdgcn_mfma_f32_16x16x32_bf16(al, Bh[b][q], acc[mt][q], 0, 0, 0);
                acc[mt][q] = __builtin_amdgcn_mfma_f32_16x16x32_bf16(ah, Bl[b][q], acc[mt][q], 0, 0, 0);
            }
        }
    };

    // prologue: A(0), A(1) staged; B(0) in regs
    loadB(0, 0);
    loadA(0); writeA(0);
    loadA(1); writeA(1);
    __syncthreads();

#pragma unroll
    for (int kk = 0; kk < 8; ++kk) {
        if (kk < 7) loadB(kk + 1, (kk + 1) & 1);
        if (kk < 6) loadA(kk + 2);
        compute(kk % 3, kk & 1);
        if (kk < 6) writeA((kk + 2) % 3);
        __syncthreads();
    }

    // epilogue: D row=(lane>>4)*4+reg, col=lane&15
    int r0 = (lane >> 4) * 4, c0 = lane & 15;
#pragma unroll
    for (int mt = 0; mt < 4; ++mt)
#pragma unroll
        for (int r = 0; r < 4; ++r) {
            int orow = i0 + mt * 16 + r0 + r;
            if (orow < n) {
#pragma unroll
                for (int q = 0; q < 4; ++q)
                    out[(size_t)orow * CH + wid * 64 + q * 16 + c0] = acc[mt][q][r];
            }
        }
}

// ---------------- mid layers sparse: 32 gathered rows per chunk, 3-pass MFMA ----------------
__global__ __launch_bounds__(256) void sparse_mid_mfma_k(
        const float* __restrict__ x,
        const unsigned short* __restrict__ Whi,
        const unsigned short* __restrict__ Wlo,
        float* __restrict__ out, const int2* __restrict__ buckets,
        const int2* __restrict__ desc, const int* __restrict__ nchunks) {
    // A image: [kk(8)][mt(2)][lane(64)][j(8)]
    __shared__ unsigned short As_hi[8192];
    __shared__ unsigned short As_lo[8192];
    __shared__ int ii[PCH];
    int nc = *nchunks;
    int t = threadIdx.x;
    int wid = t >> 6, lane = t & 63;
    int r = t >> 3, kk0 = t & 7;          // 8 threads per gathered row
    int mt_s = r >> 4, rl = r & 15;
    for (int m = blockIdx.x; m < nc; m += gridDim.x) {
        int2 d = desc[m];
        int k = d.y >> 8, len = d.y & 255;
        // ---- stage A (full K=256 for 32 rows), split hi/lo ----
        if (r < len) {
            int2 pr = buckets[d.x + r];
            if (kk0 == 0) ii[r] = pr.x;
            const float* src = x + (size_t)pr.y * CH + kk0 * 32;
#pragma unroll
            for (int kg = 0; kg < 4; ++kg) {
                float xa[8];
                floatx4 v0 = *(const floatx4*)(src + kg * 8);
                floatx4 v1 = *(const floatx4*)(src + kg * 8 + 4);
                xa[0] = v0.x; xa[1] = v0.y; xa[2] = v0.z; xa[3] = v0.w;
                xa[4] = v1.x; xa[5] = v1.y; xa[6] = v1.z; xa[7] = v1.w;
                uint4 hv, lv;
                split8_pack(xa, hv, lv);
                int ab = ((kk0 * 2 + mt_s) * 64 + kg * 16 + rl) * 8;
                *(uint4*)&As_hi[ab] = hv;
                *(uint4*)&As_lo[ab] = lv;
            }
        } else {
            if (kk0 == 0) ii[r] = -1;
            uint4 z = {0, 0, 0, 0};
#pragma unroll
            for (int kg = 0; kg < 4; ++kg) {
                int ab = ((kk0 * 2 + mt_s) * 64 + kg * 16 + rl) * 8;
                *(uint4*)&As_hi[ab] = z;
                *(uint4*)&As_lo[ab] = z;
            }
        }
        __syncthreads();
        floatx4 acc[2][4];
#pragma unroll
        for (int a = 0; a < 2; ++a)
#pragma unroll
            for (int b = 0; b < 4; ++b) acc[a][b] = floatx4{0.f, 0.f, 0.f, 0.f};
        for (int kk = 0; kk < 8; ++kk) {
            short8 ah0 = *(const short8*)&As_hi[((kk * 2 + 0) * 64 + lane) * 8];
            short8 al0 = *(const short8*)&As_lo[((kk * 2 + 0) * 64 + lane) * 8];
            short8 ah1 = *(const short8*)&As_hi[((kk * 2 + 1) * 64 + lane) * 8];
            short8 al1 = *(const short8*)&As_lo[((kk * 2 + 1) * 64 + lane) * 8];
#pragma unroll
            for (int q = 0; q < 4; ++q) {
                int nt = wid * 4 + q;
                size_t off = (((size_t)(k * 8 + kk) * 16 + nt) * 64 + lane) * 8;
                short8 bh = *(const short8*)&Whi[off];   // B direct global->VGPR (used once)
                short8 bl = *(const short8*)&Wlo[off];
                acc[0][q] = __builtin_amdgcn_mfma_f32_16x16x32_bf16(ah0, bh, acc[0][q], 0, 0, 0);
                acc[0][q] = __builtin_amdgcn_mfma_f32_16x16x32_bf16(al0, bh, acc[0][q], 0, 0, 0);
                acc[0][q] = __builtin_amdgcn_mfma_f32_16x16x32_bf16(ah0, bl, acc[0][q], 0, 0, 0);
                acc[1][q] = __builtin_amdgcn_mfma_f32_16x16x32_bf16(ah1, bh, acc[1][q], 0, 0, 0);
                acc[1][q] = __builtin_amdgcn_mfma_f32_16x16x32_bf16(al1, bh, acc[1][q], 0, 0, 0);
                acc[1][q] = __builtin_amdgcn_mfma_f32_16x16x32_bf16(ah1, bl, acc[1][q], 0, 0, 0);
            }
        }
        // ---- epilogue: atomic accumulate ----
        int r0 = (lane >> 4) * 4, c0 = lane & 15;
#pragma unroll
        for (int mt = 0; mt < 2; ++mt)
#pragma unroll
            for (int rr = 0; rr < 4; ++rr) {
                int row = mt * 16 + r0 + rr;
                int i = ii[row];
                if (i >= 0) {
#pragma unroll
                    for (int q = 0; q < 4; ++q)
                        atomicAdd(&out[(size_t)i * CH + wid * 64 + q * 16 + c0], acc[mt][q][rr]);
                }
            }
        __syncthreads();
    }
}

// ---------------- layer 4: 256 -> 2 ----------------
__device__ inline float wave_sum(float v) {
    for (int off = 32; off; off >>= 1) v += __shfl_xor(v, off);
    return v;
}

__global__ void dense4_k(const float* __restrict__ x, const float* __restrict__ Wc,
                         float* __restrict__ out, int n) {
    int wid = threadIdx.x >> 6, lane = threadIdx.x & 63;
    int i = blockIdx.x * 4 + wid;
    if (i >= n) return;
    floatx4 xv = *reinterpret_cast<const floatx4*>(x + (size_t)i * CH + lane * 4);
    floatx4 w0 = *reinterpret_cast<const floatx4*>(Wc + lane * 8);
    floatx4 w1 = *reinterpret_cast<const floatx4*>(Wc + lane * 8 + 4);
    float a0 = xv.x * w0.x + xv.y * w0.z + xv.z * w1.x + xv.w * w1.z;
    float a1 = xv.x * w0.y + xv.y * w0.w + xv.z * w1.y + xv.w * w1.w;
    a0 = wave_sum(a0);
    a1 = wave_sum(a1);
    if (lane == 0) { out[2 * i] = a0; out[2 * i + 1] = a1; }
}

__global__ void sparse4b_k(const float* __restrict__ x, const float* __restrict__ W4,
                           float* __restrict__ out, const int2* __restrict__ buckets,
                           const int2* __restrict__ desc, const int* __restrict__ nchunks) {
    int nc = *nchunks;
    int wid = threadIdx.x >> 6, lane = threadIdx.x & 63;
    for (int m = blockIdx.x; m < nc; m += gridDim.x) {
        int2 d = desc[m];
        int k = d.y >> 8, len = d.y & 255;
        const float* Wk = W4 + (size_t)k * CH * 2;
        floatx4 w0 = *reinterpret_cast<const floatx4*>(Wk + lane * 8);
        floatx4 w1 = *reinterpret_cast<const floatx4*>(Wk + lane * 8 + 4);
        for (int p = wid; p < len; p += 4) {
            int2 pr = buckets[d.x + p];
            floatx4 xv = *reinterpret_cast<const floatx4*>(x + (size_t)pr.y * CH + lane * 4);
            float a0 = xv.x * w0.x + xv.y * w0.z + xv.z * w1.x + xv.w * w1.z;
            float a1 = xv.x * w0.y + xv.y * w0.w + xv.z * w1.y + xv.w * w1.w;
            a0 = wave_sum(a0);
            a1 = wave_sum(a1);
            if (lane == 0) {
                atomicAdd(&out[2 * pr.x], a0);
                atomicAdd(&out[2 * pr.x + 1], a1);
            }
        }
    }
}

extern "C" void kernel_launch(void* const* d_in, const int* in_sizes, int n_in,
                              void* d_out, int out_size, void* d_ws, size_t ws_size,
                              hipStream_t stream) {
    const int* coords = (const int*)d_in[0];
    const float* feats = (const float*)d_in[1];
    const float* W1 = (const float*)d_in[2];
    const float* W2 = (const float*)d_in[3];
    const float* W3 = (const float*)d_in[4];
    const float* W4 = (const float*)d_in[5];
    float* out = (float*)d_out;
    int n = in_sizes[0] / 3;

    char* ws = (char*)d_ws;
    auto alloc = [&](size_t bytes) -> void* {
        void* p = (void*)ws;
        ws += (bytes + 255) & ~(size_t)255;
        return p;
    };
    ull* tbl = (ull*)alloc((size_t)HASH_SIZE * 8);
    unsigned* bm = (unsigned*)alloc((size_t)BM_WORDS * 4);
    unsigned* keys = (unsigned*)alloc((size_t)n * 4);
    int* kcnt = (int*)alloc((size_t)NSEG * 16 * 4);   // 1 counter per 64B line
    int* nchunks = (int*)alloc(4);
    int ndesc = NSEG * (SEGCAP / PCH);
    int2* desc = (int2*)alloc(sizeof(int2) * (size_t)ndesc);
    int2* buckets = (int2*)alloc(sizeof(int2) * (size_t)NSEG * SEGCAP);
    unsigned short* Whi2 = (unsigned short*)alloc((size_t)27 * 65536 * 2);
    unsigned short* Wlo2 = (unsigned short*)alloc((size_t)27 * 65536 * 2);
    unsigned short* Whi3 = (unsigned short*)alloc((size_t)27 * 65536 * 2);
    unsigned short* Wlo3 = (unsigned short*)alloc((size_t)27 * 65536 * 2);
    float* x1 = (float*)alloc((size_t)n * CH * 4);
    float* x2 = (float*)alloc((size_t)n * CH * 4);

    hipMemsetAsync(tbl, 0xFF, (size_t)HASH_SIZE * 8, stream);
    hipMemsetAsync(bm, 0, (size_t)BM_WORDS * 4, stream);
    hipMemsetAsync(kcnt, 0, (size_t)NSEG * 16 * 4, stream);

    hash_insert_k<<<(n + 255) / 256, 256, 0, stream>>>(coords, n, tbl, keys, bm);
    neighbor_bm_k<<<(n * 9 + 255) / 256, 256, 0, stream>>>(keys, n, bm, tbl, buckets, kcnt);
    chunk_desc_k<<<1, 256, 0, stream>>>(kcnt, desc, nchunks);
    prep_w_all_k<<<(27 * 65536) / 256, 256, 0, stream>>>(W2, Whi2, Wlo2);
    prep_w_all_k<<<(27 * 65536) / 256, 256, 0, stream>>>(W3, Whi3, Wlo3);

    int mtiles = (n + 63) / 64;

    // layer 1: 2 -> 256
    dense1_k<<<(n * CH + 255) / 256, 256, 0, stream>>>(feats, W1 + 13 * 2 * CH, x1, n);
    sparse1b_k<<<1024, 256, 0, stream>>>(feats, W1, x1, buckets, desc, nchunks);

    // layer 2: 256 -> 256
    dense_mid_mfma_k<<<mtiles, 256, 0, stream>>>(x1, Whi2 + (size_t)13 * 65536,
                                                 Wlo2 + (size_t)13 * 65536, x2, n);
    sparse_mid_mfma_k<<<512, 256, 0, stream>>>(x1, Whi2, Wlo2, x2, buckets, desc, nchunks);

    // layer 3: 256 -> 256
    dense_mid_mfma_k<<<mtiles, 256, 0, stream>>>(x2, Whi3 + (size_t)13 * 65536,
                                                 Wlo3 + (size_t)13 * 65536, x1, n);
    sparse_mid_mfma_k<<<512, 256, 0, stream>>>(x2, Whi3, Wlo3, x1, buckets, desc, nchunks);

    // layer 4: 256 -> 2
    dense4_k<<<(n + 3) / 4, 256, 0, stream>>>(x1, W4 + 13 * CH * 2, out, n);
    sparse4b_k<<<512, 256, 0, stream>>>(x1, W4, out, buckets, desc, nchunks);
}

// Round 10
// 304.057 us; speedup vs baseline: 1.1422x; 1.0771x over previous
//
#include <hip/hip_runtime.h>

#define HASH_BITS 19
#define HASH_SIZE (1u << HASH_BITS)
#define HASH_MASK (HASH_SIZE - 1)
#define EMPTY64 0xFFFFFFFFFFFFFFFFull
#define CH 256
#define PCH 32       // pairs per chunk in bucketed sparse kernels
#define NREP 8       // counter/bucket replicas (atomic de-contention)
#define NSEG (27 * NREP)
#define SEGCAP 4096  // pairs per (k,rep) segment
#define BM_WORDS 536704  // ceil(258^3 / 32), padded

typedef __attribute__((ext_vector_type(8))) short short8;
typedef __attribute__((ext_vector_type(4))) float floatx4;
typedef unsigned long long ull;

// packed f32x2 -> bf16x2 (src0 in low half) via HW cvt
__device__ __forceinline__ unsigned cvt_pk_bf16(float a, float b) {
    unsigned r;
    asm("v_cvt_pk_bf16_f32 %0, %1, %2" : "=v"(r) : "v"(a), "v"(b));
    return r;
}

// split 8 fp32 -> packed bf16 hi + bf16 lo (x ~= hi + lo; lo compensates hi's rounding)
__device__ inline void split8_pack(const float* xa, uint4& hv, uint4& lv) {
#pragma unroll
    for (int p = 0; p < 4; ++p) {
        unsigned hp = cvt_pk_bf16(xa[2 * p], xa[2 * p + 1]);
        float h0 = __uint_as_float(hp << 16);
        float h1 = __uint_as_float(hp & 0xFFFF0000u);
        unsigned lp = cvt_pk_bf16(xa[2 * p] - h0, xa[2 * p + 1] - h1);
        ((unsigned*)&hv)[p] = hp;
        ((unsigned*)&lv)[p] = lp;
    }
}

// ---------------- hash build: fused (key<<32 | idx) single-load table ----------------
__global__ void hash_insert_k(const int* __restrict__ coords, int n,
                              ull* __restrict__ tbl, unsigned* __restrict__ keys,
                              unsigned* __restrict__ bm) {
    int i = blockIdx.x * blockDim.x + threadIdx.x;
    if (i >= n) return;
    unsigned cx = (unsigned)(coords[3 * i + 0] + 1);
    unsigned cy = (unsigned)(coords[3 * i + 1] + 1);
    unsigned cz = (unsigned)(coords[3 * i + 2] + 1);
    unsigned key = (cx * 258u + cy) * 258u + cz;
    keys[i] = key;
    atomicOr(&bm[key >> 5], 1u << (key & 31));
    ull e = ((ull)key << 32) | (unsigned)i;
    unsigned h = (key * 2654435761u) & HASH_MASK;
    while (true) {
        ull prev = atomicCAS(&tbl[h], EMPTY64, e);
        if (prev == EMPTY64) return;
        h = (h + 1) & HASH_MASK;
    }
}

// ---------------- neighbor pairs: bitmap prefilter, replicated counters ----------------
__global__ void neighbor_bm_k(const unsigned* __restrict__ keys, int n,
                              const unsigned* __restrict__ bm,
                              const ull* __restrict__ tbl,
                              int2* __restrict__ buckets, int* __restrict__ kcnt) {
    int t = blockIdx.x * blockDim.x + threadIdx.x;
    if (t >= n * 9) return;
    int rep = blockIdx.x & (NREP - 1);
    int i = t / 9, r = t - i * 9;            // r = (dx+1)*3 + (dy+1)
    unsigned key = keys[i];
    int base = (int)key + ((r / 3 - 1) * 258 + (r % 3 - 1)) * 258;
    unsigned bA = base - 1, bB = base, bC = base + 1;
    unsigned hit0 = (bm[bA >> 5] >> (bA & 31)) & 1u;
    unsigned hit1 = (bm[bB >> 5] >> (bB & 31)) & 1u;
    unsigned hit2 = (bm[bC >> 5] >> (bC & 31)) & 1u;
#pragma unroll
    for (int dz = -1; dz <= 1; ++dz) {
        if (r == 4 && dz == 0) continue;     // center handled densely
        unsigned hit = dz < 0 ? hit0 : (dz == 0 ? hit1 : hit2);
        if (!hit) continue;
        unsigned nk = (unsigned)(base + dz);
        unsigned h = (nk * 2654435761u) & HASH_MASK;
        int j = -1;
        while (true) {
            ull e = tbl[h];
            if ((unsigned)(e >> 32) == nk) { j = (int)(e & 0xFFFFFFFFu); break; }
            if (e == EMPTY64) break;
            h = (h + 1) & HASH_MASK;
        }
        if (j >= 0) {
            int kk = 3 * r + dz + 1;
            int seg = kk * NREP + rep;
            int pos = atomicAdd(&kcnt[seg * 16], 1);
            buckets[(size_t)seg * SEGCAP + pos] = make_int2(i, j);
        }
    }
}

// ---------------- chunk descriptors over NSEG segments ----------------
__global__ void chunk_desc_k(const int* __restrict__ kcnt,
                             int2* __restrict__ desc, int* __restrict__ nchunks) {
    __shared__ int cnts[NSEG];
    __shared__ int offs[NSEG + 1];
    int t = threadIdx.x;
    if (t < NSEG) cnts[t] = kcnt[t * 16];
    __syncthreads();
    if (t == 0) {
        int acc = 0;
        for (int s = 0; s < NSEG; ++s) { offs[s] = acc; acc += (cnts[s] + PCH - 1) / PCH; }
        offs[NSEG] = acc;
        *nchunks = acc;
    }
    __syncthreads();
    if (t < NSEG) {
        int cnt = cnts[t];
        int o = offs[t];
        int k = t / NREP;
        for (int c = 0; c * PCH < cnt; ++c) {
            int len = min(PCH, cnt - c * PCH);
            desc[o + c] = make_int2(t * SEGCAP + c * PCH, (k << 8) | len);
        }
    }
}

// ---------------- pre-split ALL 27 W slices into MFMA-fragment-ordered bf16 image ----------
// image layout: [k(27)][kk(8)][nt(16)][lane(64)][j(8)] shorts
// cin = kk*32 + (lane>>4)*8 + j,  cout = nt*16 + (lane&15)
// thread = (k, kk, cout): coalesced reads (64 lanes x consecutive cout), 16B writes
__global__ void prep_w_all_k(const float* __restrict__ W, unsigned short* __restrict__ Whi,
                             unsigned short* __restrict__ Wlo) {
    int t = blockIdx.x * 256 + threadIdx.x;
    if (t >= 27 * 8 * 256) return;
    int cout = t & 255, kk = (t >> 8) & 7, k = t >> 11;
    int nt = cout >> 4, lc = cout & 15;
    const float* src = W + (size_t)k * 65536 + (size_t)kk * 32 * 256 + cout;
    size_t dbase = (((size_t)(k * 8 + kk) * 16 + nt) * 64 + lc) * 8;
#pragma unroll
    for (int kg = 0; kg < 4; ++kg) {
        float xa[8];
#pragma unroll
        for (int j = 0; j < 8; ++j) xa[j] = src[(size_t)(kg * 8 + j) * 256];
        uint4 hv, lv;
        split8_pack(xa, hv, lv);
        *(uint4*)(Whi + dbase + (size_t)kg * 16 * 8) = hv;
        *(uint4*)(Wlo + dbase + (size_t)kg * 16 * 8) = lv;
    }
}

// ---------------- layer 1: Cin=2 -> 256, dense center ----------------
__global__ void dense1_k(const float* __restrict__ x, const float* __restrict__ Wc,
                         float* __restrict__ out, int n) {
    int t = blockIdx.x * blockDim.x + threadIdx.x;
    if (t >= n * CH) return;
    int i = t >> 8, co = t & 255;
    float2 xv = *reinterpret_cast<const float2*>(x + 2 * i);
    out[t] = fmaf(xv.x, Wc[co], xv.y * Wc[CH + co]);
}

__global__ void sparse1b_k(const float* __restrict__ feats, const float* __restrict__ W1,
                           float* __restrict__ out, const int2* __restrict__ buckets,
                           const int2* __restrict__ desc, const int* __restrict__ nchunks) {
    __shared__ float xs[PCH][2];
    __shared__ int ii[PCH];
    int nc = *nchunks;
    int t = threadIdx.x;
    for (int m = blockIdx.x; m < nc; m += gridDim.x) {
        int2 d = desc[m];
        int k = d.y >> 8, len = d.y & 255;
        if (t < PCH) {
            if (t < len) {
                int2 pr = buckets[d.x + t];
                ii[t] = pr.x;
                xs[t][0] = feats[2 * pr.y];
                xs[t][1] = feats[2 * pr.y + 1];
            } else {
                ii[t] = -1;
                xs[t][0] = 0.f; xs[t][1] = 0.f;
            }
        }
        __syncthreads();
        const float* Wk = W1 + (size_t)k * 2 * CH;
        float w0 = Wk[t], w1 = Wk[CH + t];
#pragma unroll
        for (int p = 0; p < PCH; ++p) {
            int i = ii[p];
            if (i >= 0) atomicAdd(&out[(size_t)i * CH + t], fmaf(xs[p][0], w0, xs[p][1] * w1));
        }
        __syncthreads();
    }
}

// ---------------- mid layers dense center: M=64, A triple-buffer, 1 barrier/kk ----------
__global__ __launch_bounds__(256, 3) void dense_mid_mfma_k(
        const float* __restrict__ x,
        const unsigned short* __restrict__ Whi,
        const unsigned short* __restrict__ Wlo,
        float* __restrict__ out, int n) {
    __shared__ unsigned short AsH[3][2048], AsL[3][2048];
    int t = threadIdx.x;
    int wid = t >> 6, lane = t & 63;
    int i0 = blockIdx.x * 64;

    floatx4 acc[4][4];
#pragma unroll
    for (int a = 0; a < 4; ++a)
#pragma unroll
        for (int b = 0; b < 4; ++b) acc[a][b] = floatx4{0.f, 0.f, 0.f, 0.f};

    // staging role: thread t -> slot t: row = (t>>6)*16 + (t&15), kg = (t>>4)&3
    int row = ((t >> 6) << 4) + (t & 15);
    int kg = (t >> 4) & 3;
    float sok = (i0 + row < n) ? 1.f : 0.f;
    const float* sp = x + (size_t)min(i0 + row, n - 1) * CH + kg * 8;

    floatx4 ra0, ra1;
    short8 Bh[2][4], Bl[2][4];

    auto loadB = [&](int kk, int b) {
#pragma unroll
        for (int q = 0; q < 4; ++q) {
            size_t off = (((size_t)kk * 16 + wid * 4 + q) * 64 + lane) * 8;
            Bh[b][q] = *(const short8*)&Whi[off];
            Bl[b][q] = *(const short8*)&Wlo[off];
        }
    };
    auto loadA = [&](int kk) {
        ra0 = *(const floatx4*)(sp + kk * 32);
        ra1 = *(const floatx4*)(sp + kk * 32 + 4);
    };
    auto writeA = [&](int bi) {
        float xa[8];
        xa[0] = ra0.x * sok; xa[1] = ra0.y * sok; xa[2] = ra0.z * sok; xa[3] = ra0.w * sok;
        xa[4] = ra1.x * sok; xa[5] = ra1.y * sok; xa[6] = ra1.z * sok; xa[7] = ra1.w * sok;
        uint4 hv, lv;
        split8_pack(xa, hv, lv);
        *(uint4*)&AsH[bi][t * 8] = hv;
        *(uint4*)&AsL[bi][t * 8] = lv;
    };
    auto compute = [&](int bi, int b) {
#pragma unroll
        for (int mt = 0; mt < 4; ++mt) {
            short8 ah = *(const short8*)&AsH[bi][(mt * 64 + lane) * 8];
            short8 al = *(const short8*)&AsL[bi][(mt * 64 + lane) * 8];
#pragma unroll
            for (int q = 0; q < 4; ++q) {
                acc[mt][q] = __builtin_amdgcn_mfma_f32_16x16x32_bf16(ah, Bh[b][q], acc[mt][q], 0, 0, 0);
                acc[mt][q] = __builtin_amdgcn_mfma_f32_16x16x32_bf16(al, Bh[b][q], acc[mt][q], 0, 0, 0);
                acc[mt][q] = __builtin_amdgcn_mfma_f32_16x16x32_bf16(ah, Bl[b][q], acc[mt][q], 0, 0, 0);
            }
        }
    };

    // prologue: A(0), A(1) staged; B(0) in regs
    loadB(0, 0);
    loadA(0); writeA(0);
    loadA(1); writeA(1);
    __syncthreads();

#pragma unroll
    for (int kk = 0; kk < 8; ++kk) {
        if (kk < 7) loadB(kk + 1, (kk + 1) & 1);
        if (kk < 6) loadA(kk + 2);
        compute(kk % 3, kk & 1);
        if (kk < 6) writeA((kk + 2) % 3);
        __syncthreads();
    }

    // epilogue: D row=(lane>>4)*4+reg, col=lane&15
    int r0 = (lane >> 4) * 4, c0 = lane & 15;
#pragma unroll
    for (int mt = 0; mt < 4; ++mt)
#pragma unroll
        for (int r = 0; r < 4; ++r) {
            int orow = i0 + mt * 16 + r0 + r;
            if (orow < n) {
#pragma unroll
                for (int q = 0; q < 4; ++q)
                    out[(size_t)orow * CH + wid * 64 + q * 16 + c0] = acc[mt][q][r];
            }
        }
}

// ---------------- mid layers sparse: 32 gathered rows per chunk, 3-pass MFMA ----------------
__global__ __launch_bounds__(256) void sparse_mid_mfma_k(
        const float* __restrict__ x,
        const unsigned short* __restrict__ Whi,
        const unsigned short* __restrict__ Wlo,
        float* __restrict__ out, const int2* __restrict__ buckets,
        const int2* __restrict__ desc, const int* __restrict__ nchunks) {
    // A image: [kk(8)][mt(2)][lane(64)][j(8)]
    __shared__ unsigned short As_hi[8192];
    __shared__ unsigned short As_lo[8192];
    __shared__ int ii[PCH];
    int nc = *nchunks;
    int t = threadIdx.x;
    int wid = t >> 6, lane = t & 63;
    int r = t >> 3, kk0 = t & 7;          // 8 threads per gathered row
    int mt_s = r >> 4, rl = r & 15;
    for (int m = blockIdx.x; m < nc; m += gridDim.x) {
        int2 d = desc[m];
        int k = d.y >> 8, len = d.y & 255;
        // ---- stage A (full K=256 for 32 rows), split hi/lo ----
        if (r < len) {
            int2 pr = buckets[d.x + r];
            if (kk0 == 0) ii[r] = pr.x;
            const float* src = x + (size_t)pr.y * CH + kk0 * 32;
#pragma unroll
            for (int kg = 0; kg < 4; ++kg) {
                float xa[8];
                floatx4 v0 = *(const floatx4*)(src + kg * 8);
                floatx4 v1 = *(const floatx4*)(src + kg * 8 + 4);
                xa[0] = v0.x; xa[1] = v0.y; xa[2] = v0.z; xa[3] = v0.w;
                xa[4] = v1.x; xa[5] = v1.y; xa[6] = v1.z; xa[7] = v1.w;
                uint4 hv, lv;
                split8_pack(xa, hv, lv);
                int ab = ((kk0 * 2 + mt_s) * 64 + kg * 16 + rl) * 8;
                *(uint4*)&As_hi[ab] = hv;
                *(uint4*)&As_lo[ab] = lv;
            }
        } else {
            if (kk0 == 0) ii[r] = -1;
            uint4 z = {0, 0, 0, 0};
#pragma unroll
            for (int kg = 0; kg < 4; ++kg) {
                int ab = ((kk0 * 2 + mt_s) * 64 + kg * 16 + rl) * 8;
                *(uint4*)&As_hi[ab] = z;
                *(uint4*)&As_lo[ab] = z;
            }
        }
        __syncthreads();
        floatx4 acc[2][4];
#pragma unroll
        for (int a = 0; a < 2; ++a)
#pragma unroll
            for (int b = 0; b < 4; ++b) acc[a][b] = floatx4{0.f, 0.f, 0.f, 0.f};
        for (int kk = 0; kk < 8; ++kk) {
            short8 ah0 = *(const short8*)&As_hi[((kk * 2 + 0) * 64 + lane) * 8];
            short8 al0 = *(const short8*)&As_lo[((kk * 2 + 0) * 64 + lane) * 8];
            short8 ah1 = *(const short8*)&As_hi[((kk * 2 + 1) * 64 + lane) * 8];
            short8 al1 = *(const short8*)&As_lo[((kk * 2 + 1) * 64 + lane) * 8];
#pragma unroll
            for (int q = 0; q < 4; ++q) {
                int nt = wid * 4 + q;
                size_t off = (((size_t)(k * 8 + kk) * 16 + nt) * 64 + lane) * 8;
                short8 bh = *(const short8*)&Whi[off];   // B direct global->VGPR (used once)
                short8 bl = *(const short8*)&Wlo[off];
                acc[0][q] = __builtin_amdgcn_mfma_f32_16x16x32_bf16(ah0, bh, acc[0][q], 0, 0, 0);
                acc[0][q] = __builtin_amdgcn_mfma_f32_16x16x32_bf16(al0, bh, acc[0][q], 0, 0, 0);
                acc[0][q] = __builtin_amdgcn_mfma_f32_16x16x32_bf16(ah0, bl, acc[0][q], 0, 0, 0);
                acc[1][q] = __builtin_amdgcn_mfma_f32_16x16x32_bf16(ah1, bh, acc[1][q], 0, 0, 0);
                acc[1][q] = __builtin_amdgcn_mfma_f32_16x16x32_bf16(al1, bh, acc[1][q], 0, 0, 0);
                acc[1][q] = __builtin_amdgcn_mfma_f32_16x16x32_bf16(ah1, bl, acc[1][q], 0, 0, 0);
            }
        }
        // ---- epilogue: atomic accumulate ----
        int r0 = (lane >> 4) * 4, c0 = lane & 15;
#pragma unroll
        for (int mt = 0; mt < 2; ++mt)
#pragma unroll
            for (int rr = 0; rr < 4; ++rr) {
                int row = mt * 16 + r0 + rr;
                int i = ii[row];
                if (i >= 0) {
#pragma unroll
                    for (int q = 0; q < 4; ++q)
                        atomicAdd(&out[(size_t)i * CH + wid * 64 + q * 16 + c0], acc[mt][q][rr]);
                }
            }
        __syncthreads();
    }
}

// ---------------- layer 4: 256 -> 2 ----------------
__device__ inline float wave_sum(float v) {
    for (int off = 32; off; off >>= 1) v += __shfl_xor(v, off);
    return v;
}

__global__ void dense4_k(const float* __restrict__ x, const float* __restrict__ Wc,
                         float* __restrict__ out, int n) {
    int wid = threadIdx.x >> 6, lane = threadIdx.x & 63;
    int i = blockIdx.x * 4 + wid;
    if (i >= n) return;
    floatx4 xv = *reinterpret_cast<const floatx4*>(x + (size_t)i * CH + lane * 4);
    floatx4 w0 = *reinterpret_cast<const floatx4*>(Wc + lane * 8);
    floatx4 w1 = *reinterpret_cast<const floatx4*>(Wc + lane * 8 + 4);
    float a0 = xv.x * w0.x + xv.y * w0.z + xv.z * w1.x + xv.w * w1.z;
    float a1 = xv.x * w0.y + xv.y * w0.w + xv.z * w1.y + xv.w * w1.w;
    a0 = wave_sum(a0);
    a1 = wave_sum(a1);
    if (lane == 0) { out[2 * i] = a0; out[2 * i + 1] = a1; }
}

__global__ void sparse4b_k(const float* __restrict__ x, const float* __restrict__ W4,
                           float* __restrict__ out, const int2* __restrict__ buckets,
                           const int2* __restrict__ desc, const int* __restrict__ nchunks) {
    int nc = *nchunks;
    int wid = threadIdx.x >> 6, lane = threadIdx.x & 63;
    for (int m = blockIdx.x; m < nc; m += gridDim.x) {
        int2 d = desc[m];
        int k = d.y >> 8, len = d.y & 255;
        const float* Wk = W4 + (size_t)k * CH * 2;
        floatx4 w0 = *reinterpret_cast<const floatx4*>(Wk + lane * 8);
        floatx4 w1 = *reinterpret_cast<const floatx4*>(Wk + lane * 8 + 4);
        for (int p = wid; p < len; p += 4) {
            int2 pr = buckets[d.x + p];
            floatx4 xv = *reinterpret_cast<const floatx4*>(x + (size_t)pr.y * CH + lane * 4);
            float a0 = xv.x * w0.x + xv.y * w0.z + xv.z * w1.x + xv.w * w1.z;
            float a1 = xv.x * w0.y + xv.y * w0.w + xv.z * w1.y + xv.w * w1.w;
            a0 = wave_sum(a0);
            a1 = wave_sum(a1);
            if (lane == 0) {
                atomicAdd(&out[2 * pr.x], a0);
                atomicAdd(&out[2 * pr.x + 1], a1);
            }
        }
    }
}

extern "C" void kernel_launch(void* const* d_in, const int* in_sizes, int n_in,
                              void* d_out, int out_size, void* d_ws, size_t ws_size,
                              hipStream_t stream) {
    const int* coords = (const int*)d_in[0];
    const float* feats = (const float*)d_in[1];
    const float* W1 = (const float*)d_in[2];
    const float* W2 = (const float*)d_in[3];
    const float* W3 = (const float*)d_in[4];
    const float* W4 = (const float*)d_in[5];
    float* out = (float*)d_out;
    int n = in_sizes[0] / 3;

    char* ws = (char*)d_ws;
    auto alloc = [&](size_t bytes) -> void* {
        void* p = (void*)ws;
        ws += (bytes + 255) & ~(size_t)255;
        return p;
    };
    ull* tbl = (ull*)alloc((size_t)HASH_SIZE * 8);
    unsigned* bm = (unsigned*)alloc((size_t)BM_WORDS * 4);
    unsigned* keys = (unsigned*)alloc((size_t)n * 4);
    int* kcnt = (int*)alloc((size_t)NSEG * 16 * 4);   // 1 counter per 64B line
    int* nchunks = (int*)alloc(4);
    int ndesc = NSEG * (SEGCAP / PCH);
    int2* desc = (int2*)alloc(sizeof(int2) * (size_t)ndesc);
    int2* buckets = (int2*)alloc(sizeof(int2) * (size_t)NSEG * SEGCAP);
    unsigned short* Whi2 = (unsigned short*)alloc((size_t)27 * 65536 * 2);
    unsigned short* Wlo2 = (unsigned short*)alloc((size_t)27 * 65536 * 2);
    unsigned short* Whi3 = (unsigned short*)alloc((size_t)27 * 65536 * 2);
    unsigned short* Wlo3 = (unsigned short*)alloc((size_t)27 * 65536 * 2);
    float* x1 = (float*)alloc((size_t)n * CH * 4);
    float* x2 = (float*)alloc((size_t)n * CH * 4);

    hipMemsetAsync(tbl, 0xFF, (size_t)HASH_SIZE * 8, stream);
    hipMemsetAsync(bm, 0, (size_t)BM_WORDS * 4, stream);
    hipMemsetAsync(kcnt, 0, (size_t)NSEG * 16 * 4, stream);

    hash_insert_k<<<(n + 255) / 256, 256, 0, stream>>>(coords, n, tbl, keys, bm);
    neighbor_bm_k<<<(n * 9 + 255) / 256, 256, 0, stream>>>(keys, n, bm, tbl, buckets, kcnt);
    chunk_desc_k<<<1, 256, 0, stream>>>(kcnt, desc, nchunks);
    prep_w_all_k<<<(27 * 8 * 256) / 256, 256, 0, stream>>>(W2, Whi2, Wlo2);
    prep_w_all_k<<<(27 * 8 * 256) / 256, 256, 0, stream>>>(W3, Whi3, Wlo3);

    int mtiles = (n + 63) / 64;

    // layer 1: 2 -> 256
    dense1_k<<<(n * CH + 255) / 256, 256, 0, stream>>>(feats, W1 + 13 * 2 * CH, x1, n);
    sparse1b_k<<<1024, 256, 0, stream>>>(feats, W1, x1, buckets, desc, nchunks);

    // layer 2: 256 -> 256
    dense_mid_mfma_k<<<mtiles, 256, 0, stream>>>(x1, Whi2 + (size_t)13 * 65536,
                                                 Wlo2 + (size_t)13 * 65536, x2, n);
    sparse_mid_mfma_k<<<512, 256, 0, stream>>>(x1, Whi2, Wlo2, x2, buckets, desc, nchunks);

    // layer 3: 256 -> 256
    dense_mid_mfma_k<<<mtiles, 256, 0, stream>>>(x2, Whi3 + (size_t)13 * 65536,
                                                 Wlo3 + (size_t)13 * 65536, x1, n);
    sparse_mid_mfma_k<<<512, 256, 0, stream>>>(x2, Whi3, Wlo3, x1, buckets, desc, nchunks);

    // layer 4: 256 -> 2
    dense4_k<<<(n + 3) / 4, 256, 0, stream>>>(x1, W4 + 13 * CH * 2, out, n);
    sparse4b_k<<<512, 256, 0, stream>>>(x1, W4, out, buckets, desc, nchunks);
}

// Round 11
// 301.634 us; speedup vs baseline: 1.1514x; 1.0080x over previous
//
#include <hip/hip_runtime.h>

#define HASH_BITS 19
#define HASH_SIZE (1u << HASH_BITS)
#define HASH_MASK (HASH_SIZE - 1)
#define EMPTY64 0xFFFFFFFFFFFFFFFFull
#define CH 256
#define PCH 32       // pairs per chunk in bucketed sparse kernels
#define NREP 8       // counter/bucket replicas (atomic de-contention)
#define NSEG (27 * NREP)
#define SEGCAP 4096  // pairs per (k,rep) segment
#define BM_WORDS 536704  // ceil(258^3 / 32), padded

typedef __attribute__((ext_vector_type(8))) short short8;
typedef __attribute__((ext_vector_type(4))) float floatx4;
typedef unsigned long long ull;

// packed f32x2 -> bf16x2 (src0 in low half) via HW cvt
__device__ __forceinline__ unsigned cvt_pk_bf16(float a, float b) {
    unsigned r;
    asm("v_cvt_pk_bf16_f32 %0, %1, %2" : "=v"(r) : "v"(a), "v"(b));
    return r;
}

// split 8 fp32 -> packed bf16 hi + bf16 lo (x ~= hi + lo; lo compensates hi's rounding)
__device__ inline void split8_pack(const float* xa, uint4& hv, uint4& lv) {
#pragma unroll
    for (int p = 0; p < 4; ++p) {
        unsigned hp = cvt_pk_bf16(xa[2 * p], xa[2 * p + 1]);
        float h0 = __uint_as_float(hp << 16);
        float h1 = __uint_as_float(hp & 0xFFFF0000u);
        unsigned lp = cvt_pk_bf16(xa[2 * p] - h0, xa[2 * p + 1] - h1);
        ((unsigned*)&hv)[p] = hp;
        ((unsigned*)&lv)[p] = lp;
    }
}

// ---------------- hash build: fused (key<<32 | idx) single-load table ----------------
__global__ void hash_insert_k(const int* __restrict__ coords, int n,
                              ull* __restrict__ tbl, unsigned* __restrict__ keys,
                              unsigned* __restrict__ bm) {
    int i = blockIdx.x * blockDim.x + threadIdx.x;
    if (i >= n) return;
    unsigned cx = (unsigned)(coords[3 * i + 0] + 1);
    unsigned cy = (unsigned)(coords[3 * i + 1] + 1);
    unsigned cz = (unsigned)(coords[3 * i + 2] + 1);
    unsigned key = (cx * 258u + cy) * 258u + cz;
    keys[i] = key;
    atomicOr(&bm[key >> 5], 1u << (key & 31));
    ull e = ((ull)key << 32) | (unsigned)i;
    unsigned h = (key * 2654435761u) & HASH_MASK;
    while (true) {
        ull prev = atomicCAS(&tbl[h], EMPTY64, e);
        if (prev == EMPTY64) return;
        h = (h + 1) & HASH_MASK;
    }
}

// ---------------- neighbor pairs: bitmap prefilter, replicated counters ----------------
__global__ void neighbor_bm_k(const unsigned* __restrict__ keys, int n,
                              const unsigned* __restrict__ bm,
                              const ull* __restrict__ tbl,
                              int2* __restrict__ buckets, int* __restrict__ kcnt) {
    int t = blockIdx.x * blockDim.x + threadIdx.x;
    if (t >= n * 9) return;
    int rep = blockIdx.x & (NREP - 1);
    int i = t / 9, r = t - i * 9;            // r = (dx+1)*3 + (dy+1)
    unsigned key = keys[i];
    int base = (int)key + ((r / 3 - 1) * 258 + (r % 3 - 1)) * 258;
    unsigned bA = base - 1, bB = base, bC = base + 1;
    unsigned hit0 = (bm[bA >> 5] >> (bA & 31)) & 1u;
    unsigned hit1 = (bm[bB >> 5] >> (bB & 31)) & 1u;
    unsigned hit2 = (bm[bC >> 5] >> (bC & 31)) & 1u;
#pragma unroll
    for (int dz = -1; dz <= 1; ++dz) {
        if (r == 4 && dz == 0) continue;     // center handled densely
        unsigned hit = dz < 0 ? hit0 : (dz == 0 ? hit1 : hit2);
        if (!hit) continue;
        unsigned nk = (unsigned)(base + dz);
        unsigned h = (nk * 2654435761u) & HASH_MASK;
        int j = -1;
        while (true) {
            ull e = tbl[h];
            if ((unsigned)(e >> 32) == nk) { j = (int)(e & 0xFFFFFFFFu); break; }
            if (e == EMPTY64) break;
            h = (h + 1) & HASH_MASK;
        }
        if (j >= 0) {
            int kk = 3 * r + dz + 1;
            int seg = kk * NREP + rep;
            int pos = atomicAdd(&kcnt[seg * 16], 1);
            buckets[(size_t)seg * SEGCAP + pos] = make_int2(i, j);
        }
    }
}

// ---------------- chunk descriptors over NSEG segments ----------------
__global__ void chunk_desc_k(const int* __restrict__ kcnt,
                             int2* __restrict__ desc, int* __restrict__ nchunks) {
    __shared__ int cnts[NSEG];
    __shared__ int offs[NSEG + 1];
    int t = threadIdx.x;
    if (t < NSEG) cnts[t] = kcnt[t * 16];
    __syncthreads();
    if (t == 0) {
        int acc = 0;
        for (int s = 0; s < NSEG; ++s) { offs[s] = acc; acc += (cnts[s] + PCH - 1) / PCH; }
        offs[NSEG] = acc;
        *nchunks = acc;
    }
    __syncthreads();
    if (t < NSEG) {
        int cnt = cnts[t];
        int o = offs[t];
        int k = t / NREP;
        for (int c = 0; c * PCH < cnt; ++c) {
            int len = min(PCH, cnt - c * PCH);
            desc[o + c] = make_int2(t * SEGCAP + c * PCH, (k << 8) | len);
        }
    }
}

// ---------------- pre-split W2+W3 (27 slices each) into fragment-ordered bf16 images ----
// image layout: [k(27)][kk(8)][nt(16)][lane(64)][j(8)] shorts
__global__ void prep_w_all_k(const float* __restrict__ W2, const float* __restrict__ W3,
                             unsigned short* __restrict__ Whi2, unsigned short* __restrict__ Wlo2,
                             unsigned short* __restrict__ Whi3, unsigned short* __restrict__ Wlo3) {
    int t = blockIdx.x * 256 + threadIdx.x;
    const int HALF = 27 * 8 * 256;
    if (t >= 2 * HALF) return;
    const float* W = (t < HALF) ? W2 : W3;
    unsigned short* Whi = (t < HALF) ? Whi2 : Whi3;
    unsigned short* Wlo = (t < HALF) ? Wlo2 : Wlo3;
    int tt = (t < HALF) ? t : t - HALF;
    int cout = tt & 255, kk = (tt >> 8) & 7, k = tt >> 11;
    int nt = cout >> 4, lc = cout & 15;
    const float* src = W + (size_t)k * 65536 + (size_t)kk * 32 * 256 + cout;
    size_t dbase = (((size_t)(k * 8 + kk) * 16 + nt) * 64 + lc) * 8;
#pragma unroll
    for (int kg = 0; kg < 4; ++kg) {
        float xa[8];
#pragma unroll
        for (int j = 0; j < 8; ++j) xa[j] = src[(size_t)(kg * 8 + j) * 256];
        uint4 hv, lv;
        split8_pack(xa, hv, lv);
        *(uint4*)(Whi + dbase + (size_t)kg * 16 * 8) = hv;
        *(uint4*)(Wlo + dbase + (size_t)kg * 16 * 8) = lv;
    }
}

// ---------------- layer 1: Cin=2 -> 256, dense center ----------------
__global__ void dense1_k(const float* __restrict__ x, const float* __restrict__ Wc,
                         float* __restrict__ out, int n) {
    int t = blockIdx.x * blockDim.x + threadIdx.x;
    if (t >= n * CH) return;
    int i = t >> 8, co = t & 255;
    float2 xv = *reinterpret_cast<const float2*>(x + 2 * i);
    out[t] = fmaf(xv.x, Wc[co], xv.y * Wc[CH + co]);
}

__global__ void sparse1b_k(const float* __restrict__ feats, const float* __restrict__ W1,
                           float* __restrict__ out, const int2* __restrict__ buckets,
                           const int2* __restrict__ desc, const int* __restrict__ nchunks) {
    __shared__ float xs[PCH][2];
    __shared__ int ii[PCH];
    int nc = *nchunks;
    int t = threadIdx.x;
    for (int m = blockIdx.x; m < nc; m += gridDim.x) {
        int2 d = desc[m];
        int k = d.y >> 8, len = d.y & 255;
        if (t < PCH) {
            if (t < len) {
                int2 pr = buckets[d.x + t];
                ii[t] = pr.x;
                xs[t][0] = feats[2 * pr.y];
                xs[t][1] = feats[2 * pr.y + 1];
            } else {
                ii[t] = -1;
                xs[t][0] = 0.f; xs[t][1] = 0.f;
            }
        }
        __syncthreads();
        const float* Wk = W1 + (size_t)k * 2 * CH;
        float w0 = Wk[t], w1 = Wk[CH + t];
#pragma unroll
        for (int p = 0; p < PCH; ++p) {
            int i = ii[p];
            if (i >= 0) atomicAdd(&out[(size_t)i * CH + t], fmaf(xs[p][0], w0, xs[p][1] * w1));
        }
        __syncthreads();
    }
}

// ---------------- mid layers dense center: full-A-in-LDS, barrier-free kk loop ----------
// A (64 rows x K=256, split hi/lo) = 64 KB LDS, staged ONCE -> 1 barrier -> 8 kk steps
// with B global->reg double-buffered prefetch and zero barriers.
__global__ __launch_bounds__(256) void dense_mid_mfma_k(
        const float* __restrict__ x,
        const unsigned short* __restrict__ Whi,
        const unsigned short* __restrict__ Wlo,
        float* __restrict__ out, int n) {
    __shared__ unsigned short AsH[8][2048];   // [kk][slot(256)*8] = 32 KB
    __shared__ unsigned short AsL[8][2048];   // 32 KB
    int t = threadIdx.x;
    int wid = t >> 6, lane = t & 63;
    int i0 = blockIdx.x * 64;

    // ---- stage ALL of A once (thread t -> slot t; linear, conflict-free) ----
    int row = ((t >> 6) << 4) + (t & 15);
    int kg = (t >> 4) & 3;
    float sok = (i0 + row < n) ? 1.f : 0.f;
    const float* sp = x + (size_t)min(i0 + row, n - 1) * CH + kg * 8;
#pragma unroll
    for (int kk = 0; kk < 8; ++kk) {
        floatx4 v0 = *(const floatx4*)(sp + kk * 32);
        floatx4 v1 = *(const floatx4*)(sp + kk * 32 + 4);
        float xa[8];
        xa[0] = v0.x * sok; xa[1] = v0.y * sok; xa[2] = v0.z * sok; xa[3] = v0.w * sok;
        xa[4] = v1.x * sok; xa[5] = v1.y * sok; xa[6] = v1.z * sok; xa[7] = v1.w * sok;
        uint4 hv, lv;
        split8_pack(xa, hv, lv);
        *(uint4*)&AsH[kk][t * 8] = hv;
        *(uint4*)&AsL[kk][t * 8] = lv;
    }
    __syncthreads();   // the ONLY barrier

    floatx4 acc[4][4];
#pragma unroll
    for (int a = 0; a < 4; ++a)
#pragma unroll
        for (int b = 0; b < 4; ++b) acc[a][b] = floatx4{0.f, 0.f, 0.f, 0.f};

    short8 Bh[2][4], Bl[2][4];
    auto loadB = [&](int kk, int b) {
#pragma unroll
        for (int q = 0; q < 4; ++q) {
            size_t off = (((size_t)kk * 16 + wid * 4 + q) * 64 + lane) * 8;
            Bh[b][q] = *(const short8*)&Whi[off];
            Bl[b][q] = *(const short8*)&Wlo[off];
        }
    };

    loadB(0, 0);
#pragma unroll
    for (int kk = 0; kk < 8; ++kk) {
        if (kk < 7) loadB(kk + 1, (kk + 1) & 1);
        int b = kk & 1;
#pragma unroll
        for (int mt = 0; mt < 4; ++mt) {
            short8 ah = *(const short8*)&AsH[kk][(mt * 64 + lane) * 8];
            short8 al = *(const short8*)&AsL[kk][(mt * 64 + lane) * 8];
#pragma unroll
            for (int q = 0; q < 4; ++q) {
                acc[mt][q] = __builtin_amdgcn_mfma_f32_16x16x32_bf16(ah, Bh[b][q], acc[mt][q], 0, 0, 0);
                acc[mt][q] = __builtin_amdgcn_mfma_f32_16x16x32_bf16(al, Bh[b][q], acc[mt][q], 0, 0, 0);
                acc[mt][q] = __builtin_amdgcn_mfma_f32_16x16x32_bf16(ah, Bl[b][q], acc[mt][q], 0, 0, 0);
            }
        }
    }

    // epilogue: D row=(lane>>4)*4+reg, col=lane&15
    int r0 = (lane >> 4) * 4, c0 = lane & 15;
#pragma unroll
    for (int mt = 0; mt < 4; ++mt)
#pragma unroll
        for (int r = 0; r < 4; ++r) {
            int orow = i0 + mt * 16 + r0 + r;
            if (orow < n) {
#pragma unroll
                for (int q = 0; q < 4; ++q)
                    out[(size_t)orow * CH + wid * 64 + q * 16 + c0] = acc[mt][q][r];
            }
        }
}

// ---------------- mid layers sparse: 32 gathered rows/chunk, B-prefetch kk loop ----------
__global__ __launch_bounds__(256) void sparse_mid_mfma_k(
        const float* __restrict__ x,
        const unsigned short* __restrict__ Whi,
        const unsigned short* __restrict__ Wlo,
        float* __restrict__ out, const int2* __restrict__ buckets,
        const int2* __restrict__ desc, const int* __restrict__ nchunks) {
    // A image: [kk(8)][mt(2)][lane(64)][j(8)]
    __shared__ unsigned short As_hi[8192];
    __shared__ unsigned short As_lo[8192];
    __shared__ int ii[PCH];
    int nc = *nchunks;
    int t = threadIdx.x;
    int wid = t >> 6, lane = t & 63;
    int r = t >> 3, kk0 = t & 7;          // 8 threads per gathered row
    int mt_s = r >> 4, rl = r & 15;
    for (int m = blockIdx.x; m < nc; m += gridDim.x) {
        int2 d = desc[m];
        int k = d.y >> 8, len = d.y & 255;
        // ---- stage A (full K=256 for 32 rows), split hi/lo ----
        if (r < len) {
            int2 pr = buckets[d.x + r];
            if (kk0 == 0) ii[r] = pr.x;
            const float* src = x + (size_t)pr.y * CH + kk0 * 32;
#pragma unroll
            for (int kg = 0; kg < 4; ++kg) {
                float xa[8];
                floatx4 v0 = *(const floatx4*)(src + kg * 8);
                floatx4 v1 = *(const floatx4*)(src + kg * 8 + 4);
                xa[0] = v0.x; xa[1] = v0.y; xa[2] = v0.z; xa[3] = v0.w;
                xa[4] = v1.x; xa[5] = v1.y; xa[6] = v1.z; xa[7] = v1.w;
                uint4 hv, lv;
                split8_pack(xa, hv, lv);
                int ab = ((kk0 * 2 + mt_s) * 64 + kg * 16 + rl) * 8;
                *(uint4*)&As_hi[ab] = hv;
                *(uint4*)&As_lo[ab] = lv;
            }
        } else {
            if (kk0 == 0) ii[r] = -1;
            uint4 z = {0, 0, 0, 0};
#pragma unroll
            for (int kg = 0; kg < 4; ++kg) {
                int ab = ((kk0 * 2 + mt_s) * 64 + kg * 16 + rl) * 8;
                *(uint4*)&As_hi[ab] = z;
                *(uint4*)&As_lo[ab] = z;
            }
        }
        __syncthreads();
        floatx4 acc[2][4];
#pragma unroll
        for (int a = 0; a < 2; ++a)
#pragma unroll
            for (int b = 0; b < 4; ++b) acc[a][b] = floatx4{0.f, 0.f, 0.f, 0.f};

        short8 bh[2][4], bl[2][4];
        auto loadBs = [&](int kk, int b) {
#pragma unroll
            for (int q = 0; q < 4; ++q) {
                size_t off = (((size_t)(k * 8 + kk) * 16 + wid * 4 + q) * 64 + lane) * 8;
                bh[b][q] = *(const short8*)&Whi[off];
                bl[b][q] = *(const short8*)&Wlo[off];
            }
        };
        loadBs(0, 0);
#pragma unroll
        for (int kk = 0; kk < 8; ++kk) {
            if (kk < 7) loadBs(kk + 1, (kk + 1) & 1);
            int b = kk & 1;
            short8 ah0 = *(const short8*)&As_hi[((kk * 2 + 0) * 64 + lane) * 8];
            short8 al0 = *(const short8*)&As_lo[((kk * 2 + 0) * 64 + lane) * 8];
            short8 ah1 = *(const short8*)&As_hi[((kk * 2 + 1) * 64 + lane) * 8];
            short8 al1 = *(const short8*)&As_lo[((kk * 2 + 1) * 64 + lane) * 8];
#pragma unroll
            for (int q = 0; q < 4; ++q) {
                acc[0][q] = __builtin_amdgcn_mfma_f32_16x16x32_bf16(ah0, bh[b][q], acc[0][q], 0, 0, 0);
                acc[0][q] = __builtin_amdgcn_mfma_f32_16x16x32_bf16(al0, bh[b][q], acc[0][q], 0, 0, 0);
                acc[0][q] = __builtin_amdgcn_mfma_f32_16x16x32_bf16(ah0, bl[b][q], acc[0][q], 0, 0, 0);
                acc[1][q] = __builtin_amdgcn_mfma_f32_16x16x32_bf16(ah1, bh[b][q], acc[1][q], 0, 0, 0);
                acc[1][q] = __builtin_amdgcn_mfma_f32_16x16x32_bf16(al1, bh[b][q], acc[1][q], 0, 0, 0);
                acc[1][q] = __builtin_amdgcn_mfma_f32_16x16x32_bf16(ah1, bl[b][q], acc[1][q], 0, 0, 0);
            }
        }
        // ---- epilogue: atomic accumulate ----
        int r0 = (lane >> 4) * 4, c0 = lane & 15;
#pragma unroll
        for (int mt = 0; mt < 2; ++mt)
#pragma unroll
            for (int rr = 0; rr < 4; ++rr) {
                int orow = mt * 16 + r0 + rr;
                int i = ii[orow];
                if (i >= 0) {
#pragma unroll
                    for (int q = 0; q < 4; ++q)
                        atomicAdd(&out[(size_t)i * CH + wid * 64 + q * 16 + c0], acc[mt][q][rr]);
                }
            }
        __syncthreads();
    }
}

// ---------------- layer 4: 256 -> 2 ----------------
__device__ inline float wave_sum(float v) {
    for (int off = 32; off; off >>= 1) v += __shfl_xor(v, off);
    return v;
}

__global__ void dense4_k(const float* __restrict__ x, const float* __restrict__ Wc,
                         float* __restrict__ out, int n) {
    int wid = threadIdx.x >> 6, lane = threadIdx.x & 63;
    int i = blockIdx.x * 4 + wid;
    if (i >= n) return;
    floatx4 xv = *reinterpret_cast<const floatx4*>(x + (size_t)i * CH + lane * 4);
    floatx4 w0 = *reinterpret_cast<const floatx4*>(Wc + lane * 8);
    floatx4 w1 = *reinterpret_cast<const floatx4*>(Wc + lane * 8 + 4);
    float a0 = xv.x * w0.x + xv.y * w0.z + xv.z * w1.x + xv.w * w1.z;
    float a1 = xv.x * w0.y + xv.y * w0.w + xv.z * w1.y + xv.w * w1.w;
    a0 = wave_sum(a0);
    a1 = wave_sum(a1);
    if (lane == 0) { out[2 * i] = a0; out[2 * i + 1] = a1; }
}

__global__ void sparse4b_k(const float* __restrict__ x, const float* __restrict__ W4,
                           float* __restrict__ out, const int2* __restrict__ buckets,
                           const int2* __restrict__ desc, const int* __restrict__ nchunks) {
    int nc = *nchunks;
    int wid = threadIdx.x >> 6, lane = threadIdx.x & 63;
    for (int m = blockIdx.x; m < nc; m += gridDim.x) {
        int2 d = desc[m];
        int k = d.y >> 8, len = d.y & 255;
        const float* Wk = W4 + (size_t)k * CH * 2;
        floatx4 w0 = *reinterpret_cast<const floatx4*>(Wk + lane * 8);
        floatx4 w1 = *reinterpret_cast<const floatx4*>(Wk + lane * 8 + 4);
        for (int p = wid; p < len; p += 4) {
            int2 pr = buckets[d.x + p];
            floatx4 xv = *reinterpret_cast<const floatx4*>(x + (size_t)pr.y * CH + lane * 4);
            float a0 = xv.x * w0.x + xv.y * w0.z + xv.z * w1.x + xv.w * w1.z;
            float a1 = xv.x * w0.y + xv.y * w0.w + xv.z * w1.y + xv.w * w1.w;
            a0 = wave_sum(a0);
            a1 = wave_sum(a1);
            if (lane == 0) {
                atomicAdd(&out[2 * pr.x], a0);
                atomicAdd(&out[2 * pr.x + 1], a1);
            }
        }
    }
}

extern "C" void kernel_launch(void* const* d_in, const int* in_sizes, int n_in,
                              void* d_out, int out_size, void* d_ws, size_t ws_size,
                              hipStream_t stream) {
    const int* coords = (const int*)d_in[0];
    const float* feats = (const float*)d_in[1];
    const float* W1 = (const float*)d_in[2];
    const float* W2 = (const float*)d_in[3];
    const float* W3 = (const float*)d_in[4];
    const float* W4 = (const float*)d_in[5];
    float* out = (float*)d_out;
    int n = in_sizes[0] / 3;

    char* ws = (char*)d_ws;
    auto alloc = [&](size_t bytes) -> void* {
        void* p = (void*)ws;
        ws += (bytes + 255) & ~(size_t)255;
        return p;
    };
    ull* tbl = (ull*)alloc((size_t)HASH_SIZE * 8);
    unsigned* bm = (unsigned*)alloc((size_t)BM_WORDS * 4);   // bm..kcnt contiguous: one memset
    int* kcnt = (int*)alloc((size_t)NSEG * 16 * 4);          // 1 counter per 64B line
    unsigned* keys = (unsigned*)alloc((size_t)n * 4);
    int* nchunks = (int*)alloc(4);
    int ndesc = NSEG * (SEGCAP / PCH);
    int2* desc = (int2*)alloc(sizeof(int2) * (size_t)ndesc);
    int2* buckets = (int2*)alloc(sizeof(int2) * (size_t)NSEG * SEGCAP);
    unsigned short* Whi2 = (unsigned short*)alloc((size_t)27 * 65536 * 2);
    unsigned short* Wlo2 = (unsigned short*)alloc((size_t)27 * 65536 * 2);
    unsigned short* Whi3 = (unsigned short*)alloc((size_t)27 * 65536 * 2);
    unsigned short* Wlo3 = (unsigned short*)alloc((size_t)27 * 65536 * 2);
    float* x1 = (float*)alloc((size_t)n * CH * 4);
    float* x2 = (float*)alloc((size_t)n * CH * 4);

    hipMemsetAsync(tbl, 0xFF, (size_t)HASH_SIZE * 8, stream);
    hipMemsetAsync(bm, 0, (size_t)BM_WORDS * 4 + (size_t)NSEG * 16 * 4, stream);

    hash_insert_k<<<(n + 255) / 256, 256, 0, stream>>>(coords, n, tbl, keys, bm);
    neighbor_bm_k<<<(n * 9 + 255) / 256, 256, 0, stream>>>(keys, n, bm, tbl, buckets, kcnt);
    chunk_desc_k<<<1, 256, 0, stream>>>(kcnt, desc, nchunks);
    prep_w_all_k<<<(2 * 27 * 8 * 256) / 256, 256, 0, stream>>>(W2, W3, Whi2, Wlo2, Whi3, Wlo3);

    int mtiles = (n + 63) / 64;

    // layer 1: 2 -> 256
    dense1_k<<<(n * CH + 255) / 256, 256, 0, stream>>>(feats, W1 + 13 * 2 * CH, x1, n);
    sparse1b_k<<<1024, 256, 0, stream>>>(feats, W1, x1, buckets, desc, nchunks);

    // layer 2: 256 -> 256
    dense_mid_mfma_k<<<mtiles, 256, 0, stream>>>(x1, Whi2 + (size_t)13 * 65536,
                                                 Wlo2 + (size_t)13 * 65536, x2, n);
    sparse_mid_mfma_k<<<512, 256, 0, stream>>>(x1, Whi2, Wlo2, x2, buckets, desc, nchunks);

    // layer 3: 256 -> 256
    dense_mid_mfma_k<<<mtiles, 256, 0, stream>>>(x2, Whi3 + (size_t)13 * 65536,
                                                 Wlo3 + (size_t)13 * 65536, x1, n);
    sparse_mid_mfma_k<<<512, 256, 0, stream>>>(x2, Whi3, Wlo3, x1, buckets, desc, nchunks);

    // layer 4: 256 -> 2
    dense4_k<<<(n + 3) / 4, 256, 0, stream>>>(x1, W4 + 13 * CH * 2, out, n);
    sparse4b_k<<<512, 256, 0, stream>>>(x1, W4, out, buckets, desc, nchunks);
}

// Round 12
// 282.164 us; speedup vs baseline: 1.2308x; 1.0690x over previous
//
#include <hip/hip_runtime.h>

#define HASH_BITS 19
#define HASH_SIZE (1u << HASH_BITS)
#define HASH_MASK (HASH_SIZE - 1)
#define EMPTY64 0xFFFFFFFFFFFFFFFFull
#define CH 256
#define PCH 32       // pairs per chunk in bucketed sparse kernels
#define NREP 8       // counter/bucket replicas (atomic de-contention)
#define NSEG (27 * NREP)
#define SEGCAP 4096  // pairs per (k,rep) segment
#define BM_WORDS 536704  // ceil(258^3 / 32), padded

typedef __attribute__((ext_vector_type(8))) short short8;
typedef __attribute__((ext_vector_type(4))) float floatx4;
typedef unsigned long long ull;

// packed f32x2 -> bf16x2 (src0 in low half) via HW cvt
__device__ __forceinline__ unsigned cvt_pk_bf16(float a, float b) {
    unsigned r;
    asm("v_cvt_pk_bf16_f32 %0, %1, %2" : "=v"(r) : "v"(a), "v"(b));
    return r;
}

// split 8 fp32 -> packed bf16 hi + bf16 lo (x ~= hi + lo; lo compensates hi's rounding)
__device__ inline void split8_pack(const float* xa, uint4& hv, uint4& lv) {
#pragma unroll
    for (int p = 0; p < 4; ++p) {
        unsigned hp = cvt_pk_bf16(xa[2 * p], xa[2 * p + 1]);
        float h0 = __uint_as_float(hp << 16);
        float h1 = __uint_as_float(hp & 0xFFFF0000u);
        unsigned lp = cvt_pk_bf16(xa[2 * p] - h0, xa[2 * p + 1] - h1);
        ((unsigned*)&hv)[p] = hp;
        ((unsigned*)&lv)[p] = lp;
    }
}

// ---------------- hash build: fused (key<<32 | idx) single-load table ----------------
__global__ void hash_insert_k(const int* __restrict__ coords, int n,
                              ull* __restrict__ tbl, unsigned* __restrict__ keys,
                              unsigned* __restrict__ bm) {
    int i = blockIdx.x * blockDim.x + threadIdx.x;
    if (i >= n) return;
    unsigned cx = (unsigned)(coords[3 * i + 0] + 1);
    unsigned cy = (unsigned)(coords[3 * i + 1] + 1);
    unsigned cz = (unsigned)(coords[3 * i + 2] + 1);
    unsigned key = (cx * 258u + cy) * 258u + cz;
    keys[i] = key;
    atomicOr(&bm[key >> 5], 1u << (key & 31));
    ull e = ((ull)key << 32) | (unsigned)i;
    unsigned h = (key * 2654435761u) & HASH_MASK;
    while (true) {
        ull prev = atomicCAS(&tbl[h], EMPTY64, e);
        if (prev == EMPTY64) return;
        h = (h + 1) & HASH_MASK;
    }
}

// ---------------- neighbor pairs: bitmap prefilter, replicated counters ----------------
__global__ void neighbor_bm_k(const unsigned* __restrict__ keys, int n,
                              const unsigned* __restrict__ bm,
                              const ull* __restrict__ tbl,
                              int2* __restrict__ buckets, int* __restrict__ kcnt) {
    int t = blockIdx.x * blockDim.x + threadIdx.x;
    if (t >= n * 9) return;
    int rep = blockIdx.x & (NREP - 1);
    int i = t / 9, r = t - i * 9;            // r = (dx+1)*3 + (dy+1)
    unsigned key = keys[i];
    int base = (int)key + ((r / 3 - 1) * 258 + (r % 3 - 1)) * 258;
    unsigned bA = base - 1, bB = base, bC = base + 1;
    unsigned hit0 = (bm[bA >> 5] >> (bA & 31)) & 1u;
    unsigned hit1 = (bm[bB >> 5] >> (bB & 31)) & 1u;
    unsigned hit2 = (bm[bC >> 5] >> (bC & 31)) & 1u;
#pragma unroll
    for (int dz = -1; dz <= 1; ++dz) {
        if (r == 4 && dz == 0) continue;     // center handled densely
        unsigned hit = dz < 0 ? hit0 : (dz == 0 ? hit1 : hit2);
        if (!hit) continue;
        unsigned nk = (unsigned)(base + dz);
        unsigned h = (nk * 2654435761u) & HASH_MASK;
        int j = -1;
        while (true) {
            ull e = tbl[h];
            if ((unsigned)(e >> 32) == nk) { j = (int)(e & 0xFFFFFFFFu); break; }
            if (e == EMPTY64) break;
            h = (h + 1) & HASH_MASK;
        }
        if (j >= 0) {
            int kk = 3 * r + dz + 1;
            int seg = kk * NREP + rep;
            int pos = atomicAdd(&kcnt[seg * 16], 1);
            buckets[(size_t)seg * SEGCAP + pos] = make_int2(i, j);
        }
    }
}

// ---------------- chunk descriptors over NSEG segments ----------------
__global__ void chunk_desc_k(const int* __restrict__ kcnt,
                             int2* __restrict__ desc, int* __restrict__ nchunks) {
    __shared__ int cnts[NSEG];
    __shared__ int offs[NSEG + 1];
    int t = threadIdx.x;
    if (t < NSEG) cnts[t] = kcnt[t * 16];
    __syncthreads();
    if (t == 0) {
        int acc = 0;
        for (int s = 0; s < NSEG; ++s) { offs[s] = acc; acc += (cnts[s] + PCH - 1) / PCH; }
        offs[NSEG] = acc;
        *nchunks = acc;
    }
    __syncthreads();
    if (t < NSEG) {
        int cnt = cnts[t];
        int o = offs[t];
        int k = t / NREP;
        for (int c = 0; c * PCH < cnt; ++c) {
            int len = min(PCH, cnt - c * PCH);
            desc[o + c] = make_int2(t * SEGCAP + c * PCH, (k << 8) | len);
        }
    }
}

// ---------------- pre-split W2+W3 (27 slices each) into fragment-ordered bf16 images ----
// image layout: [k(27)][kk(8)][nt(16)][lane(64)][j(8)] shorts
__global__ void prep_w_all_k(const float* __restrict__ W2, const float* __restrict__ W3,
                             unsigned short* __restrict__ Whi2, unsigned short* __restrict__ Wlo2,
                             unsigned short* __restrict__ Whi3, unsigned short* __restrict__ Wlo3) {
    int t = blockIdx.x * 256 + threadIdx.x;
    const int HALF = 27 * 8 * 256;
    if (t >= 2 * HALF) return;
    const float* W = (t < HALF) ? W2 : W3;
    unsigned short* Whi = (t < HALF) ? Whi2 : Whi3;
    unsigned short* Wlo = (t < HALF) ? Wlo2 : Wlo3;
    int tt = (t < HALF) ? t : t - HALF;
    int cout = tt & 255, kk = (tt >> 8) & 7, k = tt >> 11;
    int nt = cout >> 4, lc = cout & 15;
    const float* src = W + (size_t)k * 65536 + (size_t)kk * 32 * 256 + cout;
    size_t dbase = (((size_t)(k * 8 + kk) * 16 + nt) * 64 + lc) * 8;
#pragma unroll
    for (int kg = 0; kg < 4; ++kg) {
        float xa[8];
#pragma unroll
        for (int j = 0; j < 8; ++j) xa[j] = src[(size_t)(kg * 8 + j) * 256];
        uint4 hv, lv;
        split8_pack(xa, hv, lv);
        *(uint4*)(Whi + dbase + (size_t)kg * 16 * 8) = hv;
        *(uint4*)(Wlo + dbase + (size_t)kg * 16 * 8) = lv;
    }
}

// ---------------- layer 1: Cin=2 -> 256, dense center ----------------
__global__ void dense1_k(const float* __restrict__ x, const float* __restrict__ Wc,
                         float* __restrict__ out, int n) {
    int t = blockIdx.x * blockDim.x + threadIdx.x;
    if (t >= n * CH) return;
    int i = t >> 8, co = t & 255;
    float2 xv = *reinterpret_cast<const float2*>(x + 2 * i);
    out[t] = fmaf(xv.x, Wc[co], xv.y * Wc[CH + co]);
}

__global__ void sparse1b_k(const float* __restrict__ feats, const float* __restrict__ W1,
                           float* __restrict__ out, const int2* __restrict__ buckets,
                           const int2* __restrict__ desc, const int* __restrict__ nchunks) {
    __shared__ float xs[PCH][2];
    __shared__ int ii[PCH];
    int nc = *nchunks;
    int t = threadIdx.x;
    for (int m = blockIdx.x; m < nc; m += gridDim.x) {
        int2 d = desc[m];
        int k = d.y >> 8, len = d.y & 255;
        if (t < PCH) {
            if (t < len) {
                int2 pr = buckets[d.x + t];
                ii[t] = pr.x;
                xs[t][0] = feats[2 * pr.y];
                xs[t][1] = feats[2 * pr.y + 1];
            } else {
                ii[t] = -1;
                xs[t][0] = 0.f; xs[t][1] = 0.f;
            }
        }
        __syncthreads();
        const float* Wk = W1 + (size_t)k * 2 * CH;
        float w0 = Wk[t], w1 = Wk[CH + t];
#pragma unroll
        for (int p = 0; p < PCH; ++p) {
            int i = ii[p];
            if (i >= 0) atomicAdd(&out[(size_t)i * CH + t], fmaf(xs[p][0], w0, xs[p][1] * w1));
        }
        __syncthreads();
    }
}

// ---------------- mid layers dense center: M=64, A triple-buffer, 1 barrier/kk ----------
// (R10 configuration: best measured variant — occupancy-preserving 24KB LDS)
__global__ __launch_bounds__(256, 3) void dense_mid_mfma_k(
        const float* __restrict__ x,
        const unsigned short* __restrict__ Whi,
        const unsigned short* __restrict__ Wlo,
        float* __restrict__ out, int n) {
    __shared__ unsigned short AsH[3][2048], AsL[3][2048];
    int t = threadIdx.x;
    int wid = t >> 6, lane = t & 63;
    int i0 = blockIdx.x * 64;

    floatx4 acc[4][4];
#pragma unroll
    for (int a = 0; a < 4; ++a)
#pragma unroll
        for (int b = 0; b < 4; ++b) acc[a][b] = floatx4{0.f, 0.f, 0.f, 0.f};

    // staging role: thread t -> slot t: row = (t>>6)*16 + (t&15), kg = (t>>4)&3
    int row = ((t >> 6) << 4) + (t & 15);
    int kg = (t >> 4) & 3;
    float sok = (i0 + row < n) ? 1.f : 0.f;
    const float* sp = x + (size_t)min(i0 + row, n - 1) * CH + kg * 8;

    floatx4 ra0, ra1;
    short8 Bh[2][4], Bl[2][4];

    auto loadB = [&](int kk, int b) {
#pragma unroll
        for (int q = 0; q < 4; ++q) {
            size_t off = (((size_t)kk * 16 + wid * 4 + q) * 64 + lane) * 8;
            Bh[b][q] = *(const short8*)&Whi[off];
            Bl[b][q] = *(const short8*)&Wlo[off];
        }
    };
    auto loadA = [&](int kk) {
        ra0 = *(const floatx4*)(sp + kk * 32);
        ra1 = *(const floatx4*)(sp + kk * 32 + 4);
    };
    auto writeA = [&](int bi) {
        float xa[8];
        xa[0] = ra0.x * sok; xa[1] = ra0.y * sok; xa[2] = ra0.z * sok; xa[3] = ra0.w * sok;
        xa[4] = ra1.x * sok; xa[5] = ra1.y * sok; xa[6] = ra1.z * sok; xa[7] = ra1.w * sok;
        uint4 hv, lv;
        split8_pack(xa, hv, lv);
        *(uint4*)&AsH[bi][t * 8] = hv;
        *(uint4*)&AsL[bi][t * 8] = lv;
    };
    auto compute = [&](int bi, int b) {
#pragma unroll
        for (int mt = 0; mt < 4; ++mt) {
            short8 ah = *(const short8*)&AsH[bi][(mt * 64 + lane) * 8];
            short8 al = *(const short8*)&AsL[bi][(mt * 64 + lane) * 8];
#pragma unroll
            for (int q = 0; q < 4; ++q) {
                acc[mt][q] = __builtin_amdgcn_mfma_f32_16x16x32_bf16(ah, Bh[b][q], acc[mt][q], 0, 0, 0);
                acc[mt][q] = __builtin_amdgcn_mfma_f32_16x16x32_bf16(al, Bh[b][q], acc[mt][q], 0, 0, 0);
                acc[mt][q] = __builtin_amdgcn_mfma_f32_16x16x32_bf16(ah, Bl[b][q], acc[mt][q], 0, 0, 0);
            }
        }
    };

    // prologue: A(0), A(1) staged; B(0) in regs
    loadB(0, 0);
    loadA(0); writeA(0);
    loadA(1); writeA(1);
    __syncthreads();

#pragma unroll
    for (int kk = 0; kk < 8; ++kk) {
        if (kk < 7) loadB(kk + 1, (kk + 1) & 1);
        if (kk < 6) loadA(kk + 2);
        compute(kk % 3, kk & 1);
        if (kk < 6) writeA((kk + 2) % 3);
        __syncthreads();
    }

    // epilogue: D row=(lane>>4)*4+reg, col=lane&15
    int r0 = (lane >> 4) * 4, c0 = lane & 15;
#pragma unroll
    for (int mt = 0; mt < 4; ++mt)
#pragma unroll
        for (int r = 0; r < 4; ++r) {
            int orow = i0 + mt * 16 + r0 + r;
            if (orow < n) {
#pragma unroll
                for (int q = 0; q < 4; ++q)
                    out[(size_t)orow * CH + wid * 64 + q * 16 + c0] = acc[mt][q][r];
            }
        }
}

// ---------------- mid layers sparse: 32 gathered rows/chunk, B-prefetch kk loop ----------
__global__ __launch_bounds__(256) void sparse_mid_mfma_k(
        const float* __restrict__ x,
        const unsigned short* __restrict__ Whi,
        const unsigned short* __restrict__ Wlo,
        float* __restrict__ out, const int2* __restrict__ buckets,
        const int2* __restrict__ desc, const int* __restrict__ nchunks) {
    // A image: [kk(8)][mt(2)][lane(64)][j(8)]
    __shared__ unsigned short As_hi[8192];
    __shared__ unsigned short As_lo[8192];
    __shared__ int ii[PCH];
    int nc = *nchunks;
    int t = threadIdx.x;
    int wid = t >> 6, lane = t & 63;
    int r = t >> 3, kk0 = t & 7;          // 8 threads per gathered row
    int mt_s = r >> 4, rl = r & 15;
    for (int m = blockIdx.x; m < nc; m += gridDim.x) {
        int2 d = desc[m];
        int k = d.y >> 8, len = d.y & 255;
        // ---- stage A (full K=256 for 32 rows), split hi/lo ----
        if (r < len) {
            int2 pr = buckets[d.x + r];
            if (kk0 == 0) ii[r] = pr.x;
            const float* src = x + (size_t)pr.y * CH + kk0 * 32;
#pragma unroll
            for (int kg = 0; kg < 4; ++kg) {
                float xa[8];
                floatx4 v0 = *(const floatx4*)(src + kg * 8);
                floatx4 v1 = *(const floatx4*)(src + kg * 8 + 4);
                xa[0] = v0.x; xa[1] = v0.y; xa[2] = v0.z; xa[3] = v0.w;
                xa[4] = v1.x; xa[5] = v1.y; xa[6] = v1.z; xa[7] = v1.w;
                uint4 hv, lv;
                split8_pack(xa, hv, lv);
                int ab = ((kk0 * 2 + mt_s) * 64 + kg * 16 + rl) * 8;
                *(uint4*)&As_hi[ab] = hv;
                *(uint4*)&As_lo[ab] = lv;
            }
        } else {
            if (kk0 == 0) ii[r] = -1;
            uint4 z = {0, 0, 0, 0};
#pragma unroll
            for (int kg = 0; kg < 4; ++kg) {
                int ab = ((kk0 * 2 + mt_s) * 64 + kg * 16 + rl) * 8;
                *(uint4*)&As_hi[ab] = z;
                *(uint4*)&As_lo[ab] = z;
            }
        }
        __syncthreads();
        floatx4 acc[2][4];
#pragma unroll
        for (int a = 0; a < 2; ++a)
#pragma unroll
            for (int b = 0; b < 4; ++b) acc[a][b] = floatx4{0.f, 0.f, 0.f, 0.f};

        short8 bh[2][4], bl[2][4];
        auto loadBs = [&](int kk, int b) {
#pragma unroll
            for (int q = 0; q < 4; ++q) {
                size_t off = (((size_t)(k * 8 + kk) * 16 + wid * 4 + q) * 64 + lane) * 8;
                bh[b][q] = *(const short8*)&Whi[off];
                bl[b][q] = *(const short8*)&Wlo[off];
            }
        };
        loadBs(0, 0);
#pragma unroll
        for (int kk = 0; kk < 8; ++kk) {
            if (kk < 7) loadBs(kk + 1, (kk + 1) & 1);
            int b = kk & 1;
            short8 ah0 = *(const short8*)&As_hi[((kk * 2 + 0) * 64 + lane) * 8];
            short8 al0 = *(const short8*)&As_lo[((kk * 2 + 0) * 64 + lane) * 8];
            short8 ah1 = *(const short8*)&As_hi[((kk * 2 + 1) * 64 + lane) * 8];
            short8 al1 = *(const short8*)&As_lo[((kk * 2 + 1) * 64 + lane) * 8];
#pragma unroll
            for (int q = 0; q < 4; ++q) {
                acc[0][q] = __builtin_amdgcn_mfma_f32_16x16x32_bf16(ah0, bh[b][q], acc[0][q], 0, 0, 0);
                acc[0][q] = __builtin_amdgcn_mfma_f32_16x16x32_bf16(al0, bh[b][q], acc[0][q], 0, 0, 0);
                acc[0][q] = __builtin_amdgcn_mfma_f32_16x16x32_bf16(ah0, bl[b][q], acc[0][q], 0, 0, 0);
                acc[1][q] = __builtin_amdgcn_mfma_f32_16x16x32_bf16(ah1, bh[b][q], acc[1][q], 0, 0, 0);
                acc[1][q] = __builtin_amdgcn_mfma_f32_16x16x32_bf16(al1, bh[b][q], acc[1][q], 0, 0, 0);
                acc[1][q] = __builtin_amdgcn_mfma_f32_16x16x32_bf16(ah1, bl[b][q], acc[1][q], 0, 0, 0);
            }
        }
        // ---- epilogue: atomic accumulate ----
        int r0 = (lane >> 4) * 4, c0 = lane & 15;
#pragma unroll
        for (int mt = 0; mt < 2; ++mt)
#pragma unroll
            for (int rr = 0; rr < 4; ++rr) {
                int orow = mt * 16 + r0 + rr;
                int i = ii[orow];
                if (i >= 0) {
#pragma unroll
                    for (int q = 0; q < 4; ++q)
                        atomicAdd(&out[(size_t)i * CH + wid * 64 + q * 16 + c0], acc[mt][q][rr]);
                }
            }
        __syncthreads();
    }
}

// ---------------- layer 4: 256 -> 2 ----------------
__device__ inline float wave_sum(float v) {
    for (int off = 32; off; off >>= 1) v += __shfl_xor(v, off);
    return v;
}

__global__ void dense4_k(const float* __restrict__ x, const float* __restrict__ Wc,
                         float* __restrict__ out, int n) {
    int wid = threadIdx.x >> 6, lane = threadIdx.x & 63;
    int i = blockIdx.x * 4 + wid;
    if (i >= n) return;
    floatx4 xv = *reinterpret_cast<const floatx4*>(x + (size_t)i * CH + lane * 4);
    floatx4 w0 = *reinterpret_cast<const floatx4*>(Wc + lane * 8);
    floatx4 w1 = *reinterpret_cast<const floatx4*>(Wc + lane * 8 + 4);
    float a0 = xv.x * w0.x + xv.y * w0.z + xv.z * w1.x + xv.w * w1.z;
    float a1 = xv.x * w0.y + xv.y * w0.w + xv.z * w1.y + xv.w * w1.w;
    a0 = wave_sum(a0);
    a1 = wave_sum(a1);
    if (lane == 0) { out[2 * i] = a0; out[2 * i + 1] = a1; }
}

__global__ void sparse4b_k(const float* __restrict__ x, const float* __restrict__ W4,
                           float* __restrict__ out, const int2* __restrict__ buckets,
                           const int2* __restrict__ desc, const int* __restrict__ nchunks) {
    int nc = *nchunks;
    int wid = threadIdx.x >> 6, lane = threadIdx.x & 63;
    for (int m = blockIdx.x; m < nc; m += gridDim.x) {
        int2 d = desc[m];
        int k = d.y >> 8, len = d.y & 255;
        const float* Wk = W4 + (size_t)k * CH * 2;
        floatx4 w0 = *reinterpret_cast<const floatx4*>(Wk + lane * 8);
        floatx4 w1 = *reinterpret_cast<const floatx4*>(Wk + lane * 8 + 4);
        for (int p = wid; p < len; p += 4) {
            int2 pr = buckets[d.x + p];
            floatx4 xv = *reinterpret_cast<const floatx4*>(x + (size_t)pr.y * CH + lane * 4);
            float a0 = xv.x * w0.x + xv.y * w0.z + xv.z * w1.x + xv.w * w1.z;
            float a1 = xv.x * w0.y + xv.y * w0.w + xv.z * w1.y + xv.w * w1.w;
            a0 = wave_sum(a0);
            a1 = wave_sum(a1);
            if (lane == 0) {
                atomicAdd(&out[2 * pr.x], a0);
                atomicAdd(&out[2 * pr.x + 1], a1);
            }
        }
    }
}

extern "C" void kernel_launch(void* const* d_in, const int* in_sizes, int n_in,
                              void* d_out, int out_size, void* d_ws, size_t ws_size,
                              hipStream_t stream) {
    const int* coords = (const int*)d_in[0];
    const float* feats = (const float*)d_in[1];
    const float* W1 = (const float*)d_in[2];
    const float* W2 = (const float*)d_in[3];
    const float* W3 = (const float*)d_in[4];
    const float* W4 = (const float*)d_in[5];
    float* out = (float*)d_out;
    int n = in_sizes[0] / 3;

    char* ws = (char*)d_ws;
    auto alloc = [&](size_t bytes) -> void* {
        void* p = (void*)ws;
        ws += (bytes + 255) & ~(size_t)255;
        return p;
    };
    ull* tbl = (ull*)alloc((size_t)HASH_SIZE * 8);
    unsigned* bm = (unsigned*)alloc((size_t)BM_WORDS * 4);   // bm..kcnt contiguous: one memset
    int* kcnt = (int*)alloc((size_t)NSEG * 16 * 4);          // 1 counter per 64B line
    unsigned* keys = (unsigned*)alloc((size_t)n * 4);
    int* nchunks = (int*)alloc(4);
    int ndesc = NSEG * (SEGCAP / PCH);
    int2* desc = (int2*)alloc(sizeof(int2) * (size_t)ndesc);
    int2* buckets = (int2*)alloc(sizeof(int2) * (size_t)NSEG * SEGCAP);
    unsigned short* Whi2 = (unsigned short*)alloc((size_t)27 * 65536 * 2);
    unsigned short* Wlo2 = (unsigned short*)alloc((size_t)27 * 65536 * 2);
    unsigned short* Whi3 = (unsigned short*)alloc((size_t)27 * 65536 * 2);
    unsigned short* Wlo3 = (unsigned short*)alloc((size_t)27 * 65536 * 2);
    float* x1 = (float*)alloc((size_t)n * CH * 4);
    float* x2 = (float*)alloc((size_t)n * CH * 4);

    hipMemsetAsync(tbl, 0xFF, (size_t)HASH_SIZE * 8, stream);
    hipMemsetAsync(bm, 0, (size_t)BM_WORDS * 4 + (size_t)NSEG * 16 * 4, stream);

    hash_insert_k<<<(n + 255) / 256, 256, 0, stream>>>(coords, n, tbl, keys, bm);
    neighbor_bm_k<<<(n * 9 + 255) / 256, 256, 0, stream>>>(keys, n, bm, tbl, buckets, kcnt);
    chunk_desc_k<<<1, 256, 0, stream>>>(kcnt, desc, nchunks);
    prep_w_all_k<<<(2 * 27 * 8 * 256) / 256, 256, 0, stream>>>(W2, W3, Whi2, Wlo2, Whi3, Wlo3);

    int mtiles = (n + 63) / 64;

    // layer 1: 2 -> 256
    dense1_k<<<(n * CH + 255) / 256, 256, 0, stream>>>(feats, W1 + 13 * 2 * CH, x1, n);
    sparse1b_k<<<1024, 256, 0, stream>>>(feats, W1, x1, buckets, desc, nchunks);

    // layer 2: 256 -> 256
    dense_mid_mfma_k<<<mtiles, 256, 0, stream>>>(x1, Whi2 + (size_t)13 * 65536,
                                                 Wlo2 + (size_t)13 * 65536, x2, n);
    sparse_mid_mfma_k<<<512, 256, 0, stream>>>(x1, Whi2, Wlo2, x2, buckets, desc, nchunks);

    // layer 3: 256 -> 256
    dense_mid_mfma_k<<<mtiles, 256, 0, stream>>>(x2, Whi3 + (size_t)13 * 65536,
                                                 Wlo3 + (size_t)13 * 65536, x1, n);
    sparse_mid_mfma_k<<<512, 256, 0, stream>>>(x2, Whi3, Wlo3, x1, buckets, desc, nchunks);

    // layer 4: 256 -> 2
    dense4_k<<<(n + 3) / 4, 256, 0, stream>>>(x1, W4 + 13 * CH * 2, out, n);
    sparse4b_k<<<512, 256, 0, stream>>>(x1, W4, out, buckets, desc, nchunks);
}